// Round 9
// baseline (580.648 us; speedup 1.0000x reference)
//
#include <hip/hip_runtime.h>
#include <math.h>

#define ED 128
// packed per-node row: 128 f16 w=exp(gate) + 128 f16 wv=w*v  (512 B)
#define PROW 256

typedef _Float16 f16;
typedef _Float16 half8 __attribute__((ext_vector_type(8)));
typedef _Float16 half4 __attribute__((ext_vector_type(4)));
typedef float f32x4 __attribute__((ext_vector_type(4)));

// fast tanh: ~6 VALU ops via v_exp_f32; err ~1e-6
static __device__ __forceinline__ float tanh_fast(float x) {
  float ax = fabsf(x);
  float e = __expf(2.0f * ax);
  float t = 1.0f - 2.0f / (e + 1.0f);
  return __builtin_copysignf(t, x);
}

// ---------------- encoder: h = tanh(x @ enc_W + enc_b) -> f16 ----------------
__global__ __launch_bounds__(256) void encoder_kernel(
    const float* __restrict__ x, const float* __restrict__ W,
    const float* __restrict__ b, f16* __restrict__ h, int n) {
  int idx = blockIdx.x * blockDim.x + threadIdx.x;
  if (idx >= n * ED) return;
  int i = idx >> 7, c = idx & 127;
  float v = x[i * 2 + 0] * W[c] + x[i * 2 + 1] * W[ED + c] + b[c];
  h[idx] = (f16)tanh_fast(v);
}

// ---------------- weight transpose+cast ----------------
__global__ __launch_bounds__(256) void transpose_w_kernel(
    const float* __restrict__ src, f16* __restrict__ dst, int K, int C, int total) {
  int idx = blockIdx.x * 256 + threadIdx.x;
  if (idx >= total) return;
  int kc = K * C;
  int m = idx / kc;
  int rem = idx - m * kc;
  int c = rem / K;
  int k = rem - c * K;
  dst[idx] = (f16)src[(size_t)m * kc + (size_t)k * C + c];
}

__global__ __launch_bounds__(256) void transpose3_kernel(
    const float* __restrict__ s0, const float* __restrict__ s1,
    const float* __restrict__ s2, f16* __restrict__ d0,
    f16* __restrict__ d1, f16* __restrict__ d2) {
  int idx = blockIdx.x * 256 + threadIdx.x;
  const int per = 3 * 128 * 128;
  int which = idx / per;
  if (which >= 3) return;
  int rem = idx - which * per;
  const float* s = (which == 0) ? s0 : (which == 1) ? s1 : s2;
  f16* d = (which == 0) ? d0 : (which == 1) ? d1 : d2;
  int m = rem >> 14;
  int r2 = rem & 16383;
  int c = r2 >> 7, k = r2 & 127;
  d[rem] = (f16)s[m * 16384 + k * 128 + c];
}

// ---------------- CSR build ----------------
__global__ __launch_bounds__(256) void count_deg_kernel(
    const int* __restrict__ dst, int* __restrict__ deg, int E) {
  int e = blockIdx.x * blockDim.x + threadIdx.x;
  if (e < E) atomicAdd(&deg[dst[e]], 1);
}

__global__ __launch_bounds__(1024) void scan_kernel(
    const int* __restrict__ deg, int* __restrict__ offs,
    int* __restrict__ cursor, int n) {
  __shared__ int wsum[16];
  __shared__ int carry_s;
  const int tid = threadIdx.x;
  const int lane = tid & 63;
  const int wid = tid >> 6;
  if (tid == 0) carry_s = 0;
  __syncthreads();
  for (int base = 0; base < n; base += 1024) {
    const int i = base + tid;
    const int v = (i < n) ? deg[i] : 0;
    int x = v;
    #pragma unroll
    for (int d = 1; d < 64; d <<= 1) {
      int t = __shfl_up(x, d, 64);
      if (lane >= d) x += t;
    }
    if (lane == 63) wsum[wid] = x;
    __syncthreads();
    int wbase = 0, total = 0;
    #pragma unroll
    for (int w = 0; w < 16; ++w) {
      int s = wsum[w];
      if (w < wid) wbase += s;
      total += s;
    }
    const int carry = carry_s;
    if (i < n) {
      const int excl = carry + wbase + x - v;
      offs[i] = excl;
      cursor[i] = excl;
    }
    __syncthreads();
    if (tid == 0) carry_s = carry + total;
    __syncthreads();
  }
  if (tid == 0) offs[n] = carry_s;
}

__global__ __launch_bounds__(256) void scatter_kernel(
    const int* __restrict__ src, const int* __restrict__ dst,
    int* __restrict__ cursor, int* __restrict__ ssrc, int E) {
  int e = blockIdx.x * blockDim.x + threadIdx.x;
  if (e < E) {
    int d = dst[e];
    int pos = atomicAdd(&cursor[d], 1);
    ssrc[pos] = src[e];
  }
}

// ==================== GEMM kernels: 1 wave / 16 rows / 128 cols, NO barriers =
// __launch_bounds__(64,2): grid caps occupancy at ~12 waves/CU anyway, so give
// the allocator 256 VGPRs; B-loads grouped 4 col-tiles at a time (16-32 b128
// in flight) to amortize L2 latency.

// ---------------- MGV layer 0 ----------------
__global__ __launch_bounds__(64, 2) void gemm_mgv_kernel(
    const f16* __restrict__ h,
    const f16* __restrict__ mWt, const float* __restrict__ mb,
    const f16* __restrict__ gWt, const float* __restrict__ gb,
    const f16* __restrict__ aWt, const float* __restrict__ ab,
    f16* __restrict__ P, int n) {
  __shared__ f16 Ms[16 * 128];
  char* Msb = reinterpret_cast<char*>(Ms);
  const int lane = threadIdx.x;
  const int lr = lane & 15;
  const int lg = lane >> 4;
  const int r0 = blockIdx.x * 16;

  half8 a[4];
  {
    int rr = r0 + lr;
    if (rr >= n) rr = n - 1;
    const f16* ap = h + (size_t)rr * ED + lg * 8;
    #pragma unroll
    for (int kt = 0; kt < 4; ++kt)
      a[kt] = *reinterpret_cast<const half8*>(ap + kt * 32);
  }

  // phase M: M = tanh(h@mW+mb) -> swizzled LDS stripe
  #pragma unroll
  for (int g = 0; g < 2; ++g) {
    half8 breg[4][4];
    #pragma unroll
    for (int u = 0; u < 4; ++u) {
      int col = (g * 4 + u) * 16 + lr;
      const f16* bp = mWt + (size_t)col * ED + lg * 8;
      #pragma unroll
      for (int kt = 0; kt < 4; ++kt)
        breg[u][kt] = *reinterpret_cast<const half8*>(bp + kt * 32);
    }
    #pragma unroll
    for (int u = 0; u < 4; ++u) {
      f32x4 acc = {0.f, 0.f, 0.f, 0.f};
      #pragma unroll
      for (int kt = 0; kt < 4; ++kt)
        acc = __builtin_amdgcn_mfma_f32_16x16x32_f16(a[kt], breg[u][kt], acc, 0, 0, 0);
      int col = (g * 4 + u) * 16 + lr;
      float bias = mb[col];
      #pragma unroll
      for (int j = 0; j < 4; ++j) {
        int srow = lg * 4 + j;
        int byte = srow * 256 + (((col * 2) ^ ((srow & 7) << 4)));
        *reinterpret_cast<f16*>(Msb + byte) = (f16)tanh_fast(acc[j] + bias);
      }
    }
  }

  half8 ma[4];
  #pragma unroll
  for (int kt = 0; kt < 4; ++kt) {
    int byte = lr * 256 + ((lg * 16 + kt * 64) ^ ((lr & 7) << 4));
    ma[kt] = *reinterpret_cast<const half8*>(Msb + byte);
  }

  // phase G: w = exp(M@gW + gb)
  float wreg[8][4];
  #pragma unroll
  for (int g = 0; g < 2; ++g) {
    half8 breg[4][4];
    #pragma unroll
    for (int u = 0; u < 4; ++u) {
      int col = (g * 4 + u) * 16 + lr;
      const f16* bp = gWt + (size_t)col * ED + lg * 8;
      #pragma unroll
      for (int kt = 0; kt < 4; ++kt)
        breg[u][kt] = *reinterpret_cast<const half8*>(bp + kt * 32);
    }
    #pragma unroll
    for (int u = 0; u < 4; ++u) {
      f32x4 acc = {0.f, 0.f, 0.f, 0.f};
      #pragma unroll
      for (int kt = 0; kt < 4; ++kt)
        acc = __builtin_amdgcn_mfma_f32_16x16x32_f16(ma[kt], breg[u][kt], acc, 0, 0, 0);
      int t = g * 4 + u;
      int col = t * 16 + lr;
      float bias = gb[col];
      #pragma unroll
      for (int j = 0; j < 4; ++j) {
        float ww = fminf(__expf(acc[j] + bias), 60000.f);
        wreg[t][j] = ww;
        int grow = r0 + lg * 4 + j;
        if (grow < n) P[(size_t)grow * PROW + col] = (f16)ww;
      }
    }
  }

  // phase V: wv = w * tanh(M@aW + ab)
  #pragma unroll
  for (int g = 0; g < 2; ++g) {
    half8 breg[4][4];
    #pragma unroll
    for (int u = 0; u < 4; ++u) {
      int col = (g * 4 + u) * 16 + lr;
      const f16* bp = aWt + (size_t)col * ED + lg * 8;
      #pragma unroll
      for (int kt = 0; kt < 4; ++kt)
        breg[u][kt] = *reinterpret_cast<const half8*>(bp + kt * 32);
    }
    #pragma unroll
    for (int u = 0; u < 4; ++u) {
      f32x4 acc = {0.f, 0.f, 0.f, 0.f};
      #pragma unroll
      for (int kt = 0; kt < 4; ++kt)
        acc = __builtin_amdgcn_mfma_f32_16x16x32_f16(ma[kt], breg[u][kt], acc, 0, 0, 0);
      int t = g * 4 + u;
      int col = t * 16 + lr;
      float bias = ab[col];
      #pragma unroll
      for (int j = 0; j < 4; ++j) {
        int grow = r0 + lg * 4 + j;
        if (grow < n)
          P[(size_t)grow * PROW + 128 + col] = (f16)(wreg[t][j] * tanh_fast(acc[j] + bias));
      }
    }
  }
}

// ---------------- fused upd + MGV (layers 1,2) ----------------
__global__ __launch_bounds__(64, 2) void updmgv_kernel(
    const f16* __restrict__ h, const f16* __restrict__ ag,
    const f16* __restrict__ uWt, const float* __restrict__ ub,
    const f16* __restrict__ mWt, const float* __restrict__ mb,
    const f16* __restrict__ gWt, const float* __restrict__ gb,
    const f16* __restrict__ aWt, const float* __restrict__ ab,
    f16* __restrict__ hout, f16* __restrict__ P, int n) {
  __shared__ f16 Ss[16 * 128];   // stripe: holds h_new, then M
  char* Sb = reinterpret_cast<char*>(Ss);
  const int lane = threadIdx.x;
  const int lr = lane & 15;
  const int lg = lane >> 4;
  const int r0 = blockIdx.x * 16;

  half8 ah[4], aa[4];
  {
    int rr = r0 + lr;
    if (rr >= n) rr = n - 1;
    const f16* ap = h + (size_t)rr * ED + lg * 8;
    const f16* bp = ag + (size_t)rr * ED + lg * 8;
    #pragma unroll
    for (int kt = 0; kt < 4; ++kt) {
      ah[kt] = *reinterpret_cast<const half8*>(ap + kt * 32);
      aa[kt] = *reinterpret_cast<const half8*>(bp + kt * 32);
    }
  }

  // phase U: h_new = tanh([h,ag]@uW+ub) -> global + swizzled stripe
  // groups of 4 col-tiles: 32 b128 loads in flight, then 32 MFMAs
  #pragma unroll
  for (int g = 0; g < 2; ++g) {
    half8 bh[4][4], ba[4][4];
    #pragma unroll
    for (int u = 0; u < 4; ++u) {
      int col = (g * 4 + u) * 16 + lr;
      const f16* bp = uWt + (size_t)col * 256 + lg * 8;
      #pragma unroll
      for (int kt = 0; kt < 4; ++kt) {
        bh[u][kt] = *reinterpret_cast<const half8*>(bp + kt * 32);
        ba[u][kt] = *reinterpret_cast<const half8*>(bp + 128 + kt * 32);
      }
    }
    #pragma unroll
    for (int u = 0; u < 4; ++u) {
      f32x4 acc = {0.f, 0.f, 0.f, 0.f};
      #pragma unroll
      for (int kt = 0; kt < 4; ++kt)
        acc = __builtin_amdgcn_mfma_f32_16x16x32_f16(ah[kt], bh[u][kt], acc, 0, 0, 0);
      #pragma unroll
      for (int kt = 0; kt < 4; ++kt)
        acc = __builtin_amdgcn_mfma_f32_16x16x32_f16(aa[kt], ba[u][kt], acc, 0, 0, 0);
      int col = (g * 4 + u) * 16 + lr;
      float bias = ub[col];
      #pragma unroll
      for (int j = 0; j < 4; ++j) {
        f16 hv = (f16)tanh_fast(acc[j] + bias);
        int srow = lg * 4 + j;
        int byte = srow * 256 + (((col * 2) ^ ((srow & 7) << 4)));
        *reinterpret_cast<f16*>(Sb + byte) = hv;
        int grow = r0 + srow;
        if (grow < n) hout[(size_t)grow * ED + col] = hv;
      }
    }
  }

  half8 ha[4];
  #pragma unroll
  for (int kt = 0; kt < 4; ++kt) {
    int byte = lr * 256 + ((lg * 16 + kt * 64) ^ ((lr & 7) << 4));
    ha[kt] = *reinterpret_cast<const half8*>(Sb + byte);
  }

  // phase M: M = tanh(h_new@mW+mb) -> same stripe (wave-sequential reuse)
  #pragma unroll
  for (int g = 0; g < 2; ++g) {
    half8 breg[4][4];
    #pragma unroll
    for (int u = 0; u < 4; ++u) {
      int col = (g * 4 + u) * 16 + lr;
      const f16* bp = mWt + (size_t)col * ED + lg * 8;
      #pragma unroll
      for (int kt = 0; kt < 4; ++kt)
        breg[u][kt] = *reinterpret_cast<const half8*>(bp + kt * 32);
    }
    #pragma unroll
    for (int u = 0; u < 4; ++u) {
      f32x4 acc = {0.f, 0.f, 0.f, 0.f};
      #pragma unroll
      for (int kt = 0; kt < 4; ++kt)
        acc = __builtin_amdgcn_mfma_f32_16x16x32_f16(ha[kt], breg[u][kt], acc, 0, 0, 0);
      int col = (g * 4 + u) * 16 + lr;
      float bias = mb[col];
      #pragma unroll
      for (int j = 0; j < 4; ++j) {
        int srow = lg * 4 + j;
        int byte = srow * 256 + (((col * 2) ^ ((srow & 7) << 4)));
        *reinterpret_cast<f16*>(Sb + byte) = (f16)tanh_fast(acc[j] + bias);
      }
    }
  }

  half8 ma[4];
  #pragma unroll
  for (int kt = 0; kt < 4; ++kt) {
    int byte = lr * 256 + ((lg * 16 + kt * 64) ^ ((lr & 7) << 4));
    ma[kt] = *reinterpret_cast<const half8*>(Sb + byte);
  }

  // phase G
  float wreg[8][4];
  #pragma unroll
  for (int g = 0; g < 2; ++g) {
    half8 breg[4][4];
    #pragma unroll
    for (int u = 0; u < 4; ++u) {
      int col = (g * 4 + u) * 16 + lr;
      const f16* bp = gWt + (size_t)col * ED + lg * 8;
      #pragma unroll
      for (int kt = 0; kt < 4; ++kt)
        breg[u][kt] = *reinterpret_cast<const half8*>(bp + kt * 32);
    }
    #pragma unroll
    for (int u = 0; u < 4; ++u) {
      f32x4 acc = {0.f, 0.f, 0.f, 0.f};
      #pragma unroll
      for (int kt = 0; kt < 4; ++kt)
        acc = __builtin_amdgcn_mfma_f32_16x16x32_f16(ma[kt], breg[u][kt], acc, 0, 0, 0);
      int t = g * 4 + u;
      int col = t * 16 + lr;
      float bias = gb[col];
      #pragma unroll
      for (int j = 0; j < 4; ++j) {
        float ww = fminf(__expf(acc[j] + bias), 60000.f);
        wreg[t][j] = ww;
        int grow = r0 + lg * 4 + j;
        if (grow < n) P[(size_t)grow * PROW + col] = (f16)ww;
      }
    }
  }

  // phase V
  #pragma unroll
  for (int g = 0; g < 2; ++g) {
    half8 breg[4][4];
    #pragma unroll
    for (int u = 0; u < 4; ++u) {
      int col = (g * 4 + u) * 16 + lr;
      const f16* bp = aWt + (size_t)col * ED + lg * 8;
      #pragma unroll
      for (int kt = 0; kt < 4; ++kt)
        breg[u][kt] = *reinterpret_cast<const half8*>(bp + kt * 32);
    }
    #pragma unroll
    for (int u = 0; u < 4; ++u) {
      f32x4 acc = {0.f, 0.f, 0.f, 0.f};
      #pragma unroll
      for (int kt = 0; kt < 4; ++kt)
        acc = __builtin_amdgcn_mfma_f32_16x16x32_f16(ma[kt], breg[u][kt], acc, 0, 0, 0);
      int t = g * 4 + u;
      int col = t * 16 + lr;
      float bias = ab[col];
      #pragma unroll
      for (int j = 0; j < 4; ++j) {
        int grow = r0 + lg * 4 + j;
        if (grow < n)
          P[(size_t)grow * PROW + 128 + col] = (f16)(wreg[t][j] * tanh_fast(acc[j] + bias));
      }
    }
  }
}

// ---------------- fused upd + decoder (layer 2 end) ----------------
__global__ __launch_bounds__(64, 2) void upddec_kernel(
    const f16* __restrict__ h, const f16* __restrict__ ag,
    const f16* __restrict__ uWt, const float* __restrict__ ub,
    const f16* __restrict__ d1Wt, const float* __restrict__ d1b,
    const float* __restrict__ d2W, const float* __restrict__ d2b,
    float* __restrict__ out, int n) {
  __shared__ f16 Ss[16 * 128];
  char* Sb = reinterpret_cast<char*>(Ss);
  const int lane = threadIdx.x;
  const int lr = lane & 15;
  const int lg = lane >> 4;
  const int r0 = blockIdx.x * 16;

  half8 ah[4], aa[4];
  {
    int rr = r0 + lr;
    if (rr >= n) rr = n - 1;
    const f16* ap = h + (size_t)rr * ED + lg * 8;
    const f16* bp = ag + (size_t)rr * ED + lg * 8;
    #pragma unroll
    for (int kt = 0; kt < 4; ++kt) {
      ah[kt] = *reinterpret_cast<const half8*>(ap + kt * 32);
      aa[kt] = *reinterpret_cast<const half8*>(bp + kt * 32);
    }
  }

  // phase U: h3 -> swizzled stripe only
  #pragma unroll
  for (int g = 0; g < 2; ++g) {
    half8 bh[4][4], ba[4][4];
    #pragma unroll
    for (int u = 0; u < 4; ++u) {
      int col = (g * 4 + u) * 16 + lr;
      const f16* bp = uWt + (size_t)col * 256 + lg * 8;
      #pragma unroll
      for (int kt = 0; kt < 4; ++kt) {
        bh[u][kt] = *reinterpret_cast<const half8*>(bp + kt * 32);
        ba[u][kt] = *reinterpret_cast<const half8*>(bp + 128 + kt * 32);
      }
    }
    #pragma unroll
    for (int u = 0; u < 4; ++u) {
      f32x4 acc = {0.f, 0.f, 0.f, 0.f};
      #pragma unroll
      for (int kt = 0; kt < 4; ++kt)
        acc = __builtin_amdgcn_mfma_f32_16x16x32_f16(ah[kt], bh[u][kt], acc, 0, 0, 0);
      #pragma unroll
      for (int kt = 0; kt < 4; ++kt)
        acc = __builtin_amdgcn_mfma_f32_16x16x32_f16(aa[kt], ba[u][kt], acc, 0, 0, 0);
      int col = (g * 4 + u) * 16 + lr;
      float bias = ub[col];
      #pragma unroll
      for (int j = 0; j < 4; ++j) {
        int srow = lg * 4 + j;
        int byte = srow * 256 + (((col * 2) ^ ((srow & 7) << 4)));
        *reinterpret_cast<f16*>(Sb + byte) = (f16)tanh_fast(acc[j] + bias);
      }
    }
  }

  half8 ha[4];
  #pragma unroll
  for (int kt = 0; kt < 4; ++kt) {
    int byte = lr * 256 + ((lg * 16 + kt * 64) ^ ((lr & 7) << 4));
    ha[kt] = *reinterpret_cast<const half8*>(Sb + byte);
  }

  // decoder: y = tanh(h3@d1W+d1b); out = y@d2W + d2b (64 cols)
  float rowsum[4] = {0.f, 0.f, 0.f, 0.f};
  {
    half8 breg[4][4];
    #pragma unroll
    for (int t = 0; t < 4; ++t) {
      int col = t * 16 + lr;
      const f16* bp = d1Wt + (size_t)col * ED + lg * 8;
      #pragma unroll
      for (int kt = 0; kt < 4; ++kt)
        breg[t][kt] = *reinterpret_cast<const half8*>(bp + kt * 32);
    }
    #pragma unroll
    for (int t = 0; t < 4; ++t) {
      f32x4 acc = {0.f, 0.f, 0.f, 0.f};
      #pragma unroll
      for (int kt = 0; kt < 4; ++kt)
        acc = __builtin_amdgcn_mfma_f32_16x16x32_f16(ha[kt], breg[t][kt], acc, 0, 0, 0);
      int col = t * 16 + lr;
      float b1 = d1b[col], w2 = d2W[col];
      #pragma unroll
      for (int j = 0; j < 4; ++j) rowsum[j] += tanh_fast(acc[j] + b1) * w2;
    }
  }
  #pragma unroll
  for (int d = 1; d < 16; d <<= 1) {
    #pragma unroll
    for (int j = 0; j < 4; ++j) rowsum[j] += __shfl_xor(rowsum[j], d, 64);
  }
  if (lr == 0) {
    #pragma unroll
    for (int j = 0; j < 4; ++j) {
      int grow = r0 + lg * 4 + j;
      if (grow < n) out[grow] = rowsum[j] + d2b[0];
    }
  }
}

// ---------------- edge aggregation: one wave per dst node, pure gather-sum ---
__global__ __launch_bounds__(256) void edge_aggr_kernel(
    const int* __restrict__ offs, const int* __restrict__ ssrc,
    const f16* __restrict__ P, f16* __restrict__ aggr, int n) {
  int i = blockIdx.x * 4 + (threadIdx.x >> 6);
  if (i >= n) return;
  int lane = threadIdx.x & 63;
  int s0 = offs[i], s1 = offs[i + 1];
  const char* Pb = reinterpret_cast<const char*>(P);

  float4 acc = {0.f, 0.f, 0.f, 0.f};
  #pragma unroll 4
  for (int e = s0; e < s1; ++e) {
    int sn = ssrc[e];
    half4 x = *reinterpret_cast<const half4*>(Pb + (size_t)sn * 512 + lane * 8);
    acc.x += (float)x.x;
    acc.y += (float)x.y;
    acc.z += (float)x.z;
    acc.w += (float)x.w;
  }
  float px = __shfl(acc.x, lane ^ 32, 64);
  float py = __shfl(acc.y, lane ^ 32, 64);
  float pz = __shfl(acc.z, lane ^ 32, 64);
  float pw = __shfl(acc.w, lane ^ 32, 64);
  if (lane >= 32) {
    half4 o;
    o.x = (f16)(acc.x / (px + 1e-16f));
    o.y = (f16)(acc.y / (py + 1e-16f));
    o.z = (f16)(acc.z / (pz + 1e-16f));
    o.w = (f16)(acc.w / (pw + 1e-16f));
    *reinterpret_cast<half4*>(
        reinterpret_cast<char*>(aggr) + (size_t)i * 256 + (size_t)(lane - 32) * 8) = o;
  }
}

// ---------------- host ----------------
extern "C" void kernel_launch(void* const* d_in, const int* in_sizes, int n_in,
                              void* d_out, int out_size, void* d_ws, size_t ws_size,
                              hipStream_t stream) {
  const float* node_feature = (const float*)d_in[0];
  const int*   edge_index   = (const int*)d_in[1];
  const float* enc_W  = (const float*)d_in[3];
  const float* enc_b  = (const float*)d_in[4];
  const float* gate_W = (const float*)d_in[5];
  const float* gate_b = (const float*)d_in[6];
  const float* att_W  = (const float*)d_in[7];
  const float* att_b  = (const float*)d_in[8];
  const float* msg_W  = (const float*)d_in[9];
  const float* msg_b  = (const float*)d_in[10];
  const float* upd_W  = (const float*)d_in[11];
  const float* upd_b  = (const float*)d_in[12];
  const float* dec1_W = (const float*)d_in[13];
  const float* dec1_b = (const float*)d_in[14];
  const float* dec2_W = (const float*)d_in[15];
  const float* dec2_b = (const float*)d_in[16];

  const int n = in_sizes[0] / 2;   // 50000
  const int E = in_sizes[1] / 2;   // 800000
  const int* src = edge_index;
  const int* dst = edge_index + E;

  char* ws = (char*)d_ws;
  size_t off = 0;
  auto alloc = [&](size_t bytes) -> void* {
    void* p = ws + off;
    off += (bytes + 255) & ~(size_t)255;
    return p;
  };
  f16* hA   = (f16*)alloc((size_t)n * ED * 2);
  f16* hB   = (f16*)alloc((size_t)n * ED * 2);
  f16* P    = (f16*)alloc((size_t)n * PROW * 2);
  f16* aggr = (f16*)alloc((size_t)n * ED * 2);
  int* deg    = (int*)alloc((size_t)n * 4);
  int* offs   = (int*)alloc((size_t)(n + 1) * 4);
  int* cursor = (int*)alloc((size_t)n * 4);
  int* ssrc   = (int*)alloc((size_t)E * 4);
  f16* msgT  = (f16*)alloc((size_t)3 * ED * ED * 2);
  f16* gateT = (f16*)alloc((size_t)3 * ED * ED * 2);
  f16* attT  = (f16*)alloc((size_t)3 * ED * ED * 2);
  f16* updT  = (f16*)alloc((size_t)3 * ED * 2 * ED * 2);
  f16* dec1T = (f16*)alloc((size_t)ED * 64 * 2);

  // weight prep (once per call)
  {
    int tot3 = 3 * 3 * ED * ED;
    transpose3_kernel<<<(tot3 + 255) / 256, 256, 0, stream>>>(
        msg_W, gate_W, att_W, msgT, gateT, attT);
    int totu = 3 * 2 * ED * ED;
    transpose_w_kernel<<<(totu + 255) / 256, 256, 0, stream>>>(
        upd_W, updT, 2 * ED, ED, totu);
    int totd = ED * 64;
    transpose_w_kernel<<<(totd + 255) / 256, 256, 0, stream>>>(
        dec1_W, dec1T, ED, 64, totd);
  }

  // CSR build (once per call)
  hipMemsetAsync(deg, 0, (size_t)n * 4, stream);
  count_deg_kernel<<<(E + 255) / 256, 256, 0, stream>>>(dst, deg, E);
  scan_kernel<<<1, 1024, 0, stream>>>(deg, offs, cursor, n);
  scatter_kernel<<<(E + 255) / 256, 256, 0, stream>>>(src, dst, cursor, ssrc, E);

  // encoder
  encoder_kernel<<<((size_t)n * ED + 255) / 256, 256, 0, stream>>>(
      node_feature, enc_W, enc_b, hA, n);

  const int gemm_grid = (n + 15) / 16;   // 1 wave per 16 rows
  const int aggr_grid = (n + 3) / 4;

  // layer 0 MGV
  gemm_mgv_kernel<<<gemm_grid, 64, 0, stream>>>(
      hA, msgT, msg_b, gateT, gate_b, attT, att_b, P, n);
  edge_aggr_kernel<<<aggr_grid, 256, 0, stream>>>(offs, ssrc, P, aggr, n);

  // upd0 + MGV1
  updmgv_kernel<<<gemm_grid, 64, 0, stream>>>(
      hA, aggr, updT, upd_b,
      msgT + (size_t)1 * ED * ED, msg_b + ED,
      gateT + (size_t)1 * ED * ED, gate_b + ED,
      attT + (size_t)1 * ED * ED, att_b + ED,
      hB, P, n);
  edge_aggr_kernel<<<aggr_grid, 256, 0, stream>>>(offs, ssrc, P, aggr, n);

  // upd1 + MGV2
  updmgv_kernel<<<gemm_grid, 64, 0, stream>>>(
      hB, aggr, updT + (size_t)1 * 2 * ED * ED, upd_b + ED,
      msgT + (size_t)2 * ED * ED, msg_b + 2 * ED,
      gateT + (size_t)2 * ED * ED, gate_b + 2 * ED,
      attT + (size_t)2 * ED * ED, att_b + 2 * ED,
      hA, P, n);
  edge_aggr_kernel<<<aggr_grid, 256, 0, stream>>>(offs, ssrc, P, aggr, n);

  // upd2 + decoder
  upddec_kernel<<<gemm_grid, 64, 0, stream>>>(
      hA, aggr, updT + (size_t)2 * 2 * ED * ED, upd_b + 2 * ED,
      dec1T, dec1_b, dec2_W, dec2_b, (float*)d_out, n);
}

// Round 10
// 467.062 us; speedup vs baseline: 1.2432x; 1.2432x over previous
//
#include <hip/hip_runtime.h>
#include <math.h>

#define ED 128
// packed per-node row: 128 f16 w=exp(gate) + 128 f16 wv=w*v  (512 B)
#define PROW 256

typedef _Float16 f16;
typedef _Float16 half8 __attribute__((ext_vector_type(8)));
typedef _Float16 half4 __attribute__((ext_vector_type(4)));
typedef float f32x4 __attribute__((ext_vector_type(4)));

// fast tanh: ~6 VALU ops via v_exp_f32; err ~1e-6
static __device__ __forceinline__ float tanh_fast(float x) {
  float ax = fabsf(x);
  float e = __expf(2.0f * ax);
  float t = 1.0f - 2.0f / (e + 1.0f);
  return __builtin_copysignf(t, x);
}

// ---- stage a [rows][rowBytes] f16 weight panel into swizzled LDS ----
// LDS[row*256 + (off ^ ((row&7)<<4))] = src[row*rowBytes + rowOff + off]
// (involution: stage with the same XOR on the source side, 16B chunks)
static __device__ __forceinline__ void stage_w(
    const char* __restrict__ gsrc, int rowBytes, int rowOff,
    char* lds, int tid, int nIter) {
  #pragma unroll
  for (int i = 0; i < nIter; ++i) {
    int b = (i * 256 + tid) * 16;
    int row = b >> 8;
    int sw = (b & 255) ^ ((row & 7) << 4);
    float4 v = *reinterpret_cast<const float4*>(
        gsrc + (size_t)row * rowBytes + rowOff + sw);
    *reinterpret_cast<float4*>(lds + b) = v;
  }
}

static __device__ __forceinline__ half8 read_w(const char* Wsb, int col, int koff) {
  int byte = col * 256 + (koff ^ ((col & 7) << 4));
  return *reinterpret_cast<const half8*>(Wsb + byte);
}

// ---------------- encoder: h = tanh(x @ enc_W + enc_b) -> f16 ----------------
__global__ __launch_bounds__(256) void encoder_kernel(
    const float* __restrict__ x, const float* __restrict__ W,
    const float* __restrict__ b, f16* __restrict__ h, int n) {
  int idx = blockIdx.x * blockDim.x + threadIdx.x;
  if (idx >= n * ED) return;
  int i = idx >> 7, c = idx & 127;
  float v = x[i * 2 + 0] * W[c] + x[i * 2 + 1] * W[ED + c] + b[c];
  h[idx] = (f16)tanh_fast(v);
}

// ---------------- weight transpose+cast ----------------
__global__ __launch_bounds__(256) void transpose_w_kernel(
    const float* __restrict__ src, f16* __restrict__ dst, int K, int C, int total) {
  int idx = blockIdx.x * 256 + threadIdx.x;
  if (idx >= total) return;
  int kc = K * C;
  int m = idx / kc;
  int rem = idx - m * kc;
  int c = rem / K;
  int k = rem - c * K;
  dst[idx] = (f16)src[(size_t)m * kc + (size_t)k * C + c];
}

__global__ __launch_bounds__(256) void transpose3_kernel(
    const float* __restrict__ s0, const float* __restrict__ s1,
    const float* __restrict__ s2, f16* __restrict__ d0,
    f16* __restrict__ d1, f16* __restrict__ d2) {
  int idx = blockIdx.x * 256 + threadIdx.x;
  const int per = 3 * 128 * 128;
  int which = idx / per;
  if (which >= 3) return;
  int rem = idx - which * per;
  const float* s = (which == 0) ? s0 : (which == 1) ? s1 : s2;
  f16* d = (which == 0) ? d0 : (which == 1) ? d1 : d2;
  int m = rem >> 14;
  int r2 = rem & 16383;
  int c = r2 >> 7, k = r2 & 127;
  d[rem] = (f16)s[m * 16384 + k * 128 + c];
}

// ---------------- CSR build ----------------
__global__ __launch_bounds__(256) void count_deg_kernel(
    const int* __restrict__ dst, int* __restrict__ deg, int E) {
  int e = blockIdx.x * blockDim.x + threadIdx.x;
  if (e < E) atomicAdd(&deg[dst[e]], 1);
}

__global__ __launch_bounds__(1024) void scan_kernel(
    const int* __restrict__ deg, int* __restrict__ offs,
    int* __restrict__ cursor, int n) {
  __shared__ int wsum[16];
  __shared__ int carry_s;
  const int tid = threadIdx.x;
  const int lane = tid & 63;
  const int wid = tid >> 6;
  if (tid == 0) carry_s = 0;
  __syncthreads();
  for (int base = 0; base < n; base += 1024) {
    const int i = base + tid;
    const int v = (i < n) ? deg[i] : 0;
    int x = v;
    #pragma unroll
    for (int d = 1; d < 64; d <<= 1) {
      int t = __shfl_up(x, d, 64);
      if (lane >= d) x += t;
    }
    if (lane == 63) wsum[wid] = x;
    __syncthreads();
    int wbase = 0, total = 0;
    #pragma unroll
    for (int w = 0; w < 16; ++w) {
      int s = wsum[w];
      if (w < wid) wbase += s;
      total += s;
    }
    const int carry = carry_s;
    if (i < n) {
      const int excl = carry + wbase + x - v;
      offs[i] = excl;
      cursor[i] = excl;
    }
    __syncthreads();
    if (tid == 0) carry_s = carry + total;
    __syncthreads();
  }
  if (tid == 0) offs[n] = carry_s;
}

__global__ __launch_bounds__(256) void scatter_kernel(
    const int* __restrict__ src, const int* __restrict__ dst,
    int* __restrict__ cursor, int* __restrict__ ssrc, int E) {
  int e = blockIdx.x * blockDim.x + threadIdx.x;
  if (e < E) {
    int d = dst[e];
    int pos = atomicAdd(&cursor[d], 1);
    ssrc[pos] = src[e];
  }
}

// ==================== GEMM kernels: 256 thr = 4 waves x 16-row stripes,
// weights staged in swizzled LDS once per block per phase ====================

// ---------------- MGV layer 0 ----------------
__global__ __launch_bounds__(256) void gemm_mgv_kernel(
    const f16* __restrict__ h,
    const f16* __restrict__ mWt, const float* __restrict__ mb,
    const f16* __restrict__ gWt, const float* __restrict__ gb,
    const f16* __restrict__ aWt, const float* __restrict__ ab,
    f16* __restrict__ P, int n) {
  __shared__ f16 Ws[128 * 128];   // 32 KB weight panel
  __shared__ f16 Ss[64 * 128];    // 16 KB stripe buffer (M)
  char* Wsb = reinterpret_cast<char*>(Ws);
  char* Sb = reinterpret_cast<char*>(Ss);
  const int tid = threadIdx.x;
  const int w = tid >> 6, lane = tid & 63;
  const int lr = lane & 15, lg = lane >> 4;
  const int r0 = blockIdx.x * 64 + w * 16;

  half8 a[4];
  {
    int rr = r0 + lr;
    if (rr >= n) rr = n - 1;
    const f16* ap = h + (size_t)rr * ED + lg * 8;
    #pragma unroll
    for (int kt = 0; kt < 4; ++kt)
      a[kt] = *reinterpret_cast<const half8*>(ap + kt * 32);
  }

  // ---- phase M: M = tanh(h@mW+mb) -> stripe ----
  stage_w((const char*)mWt, 256, 0, Wsb, tid, 8);
  __syncthreads();
  #pragma unroll
  for (int t = 0; t < 8; ++t) {
    f32x4 acc = {0.f, 0.f, 0.f, 0.f};
    int col = t * 16 + lr;
    #pragma unroll
    for (int kt = 0; kt < 4; ++kt)
      acc = __builtin_amdgcn_mfma_f32_16x16x32_f16(a[kt], read_w(Wsb, col, lg * 16 + kt * 64), acc, 0, 0, 0);
    float bias = mb[col];
    #pragma unroll
    for (int j = 0; j < 4; ++j) {
      int srow = w * 16 + lg * 4 + j;
      int byte = srow * 256 + (((col * 2) ^ ((srow & 7) << 4)));
      *reinterpret_cast<f16*>(Sb + byte) = (f16)tanh_fast(acc[j] + bias);
    }
  }
  half8 ma[4];
  {
    int lrow = w * 16 + lr;
    #pragma unroll
    for (int kt = 0; kt < 4; ++kt) {
      int byte = lrow * 256 + ((lg * 16 + kt * 64) ^ ((lrow & 7) << 4));
      ma[kt] = *reinterpret_cast<const half8*>(Sb + byte);
    }
  }
  __syncthreads();

  // ---- phase G: w = exp(M@gW+gb) ----
  stage_w((const char*)gWt, 256, 0, Wsb, tid, 8);
  __syncthreads();
  float wreg[8][4];
  #pragma unroll
  for (int t = 0; t < 8; ++t) {
    f32x4 acc = {0.f, 0.f, 0.f, 0.f};
    int col = t * 16 + lr;
    #pragma unroll
    for (int kt = 0; kt < 4; ++kt)
      acc = __builtin_amdgcn_mfma_f32_16x16x32_f16(ma[kt], read_w(Wsb, col, lg * 16 + kt * 64), acc, 0, 0, 0);
    float bias = gb[col];
    #pragma unroll
    for (int j = 0; j < 4; ++j) {
      float ww = fminf(__expf(acc[j] + bias), 60000.f);
      wreg[t][j] = ww;
      int grow = r0 + lg * 4 + j;
      if (grow < n) P[(size_t)grow * PROW + col] = (f16)ww;
    }
  }
  __syncthreads();

  // ---- phase V: wv = w * tanh(M@aW+ab) ----
  stage_w((const char*)aWt, 256, 0, Wsb, tid, 8);
  __syncthreads();
  #pragma unroll
  for (int t = 0; t < 8; ++t) {
    f32x4 acc = {0.f, 0.f, 0.f, 0.f};
    int col = t * 16 + lr;
    #pragma unroll
    for (int kt = 0; kt < 4; ++kt)
      acc = __builtin_amdgcn_mfma_f32_16x16x32_f16(ma[kt], read_w(Wsb, col, lg * 16 + kt * 64), acc, 0, 0, 0);
    float bias = ab[col];
    #pragma unroll
    for (int j = 0; j < 4; ++j) {
      int grow = r0 + lg * 4 + j;
      if (grow < n)
        P[(size_t)grow * PROW + 128 + col] = (f16)(wreg[t][j] * tanh_fast(acc[j] + bias));
    }
  }
}

// ---------------- fused upd + MGV (layers 1,2) ----------------
__global__ __launch_bounds__(256) void updmgv_kernel(
    const f16* __restrict__ h, const f16* __restrict__ ag,
    const f16* __restrict__ uWt, const float* __restrict__ ub,
    const f16* __restrict__ mWt, const float* __restrict__ mb,
    const f16* __restrict__ gWt, const float* __restrict__ gb,
    const f16* __restrict__ aWt, const float* __restrict__ ab,
    f16* __restrict__ hout, f16* __restrict__ P, int n) {
  __shared__ f16 Ws[128 * 128];   // 32 KB weight panel
  __shared__ f16 Ss[64 * 128];    // 16 KB stripe buffer (h_new, then M)
  char* Wsb = reinterpret_cast<char*>(Ws);
  char* Sb = reinterpret_cast<char*>(Ss);
  const int tid = threadIdx.x;
  const int w = tid >> 6, lane = tid & 63;
  const int lr = lane & 15, lg = lane >> 4;
  const int r0 = blockIdx.x * 64 + w * 16;

  half8 ah[4], aa[4];
  {
    int rr = r0 + lr;
    if (rr >= n) rr = n - 1;
    const f16* ap = h + (size_t)rr * ED + lg * 8;
    const f16* bp = ag + (size_t)rr * ED + lg * 8;
    #pragma unroll
    for (int kt = 0; kt < 4; ++kt) {
      ah[kt] = *reinterpret_cast<const half8*>(ap + kt * 32);
      aa[kt] = *reinterpret_cast<const half8*>(bp + kt * 32);
    }
  }

  // ---- phase U: h_new = tanh([h,ag]@uW+ub), uW staged in two 32KB halves ----
  stage_w((const char*)uWt, 512, 0, Wsb, tid, 8);      // h-part (k 0..127)
  __syncthreads();
  f32x4 acc8[8];
  #pragma unroll
  for (int t = 0; t < 8; ++t) {
    f32x4 acc = {0.f, 0.f, 0.f, 0.f};
    int col = t * 16 + lr;
    #pragma unroll
    for (int kt = 0; kt < 4; ++kt)
      acc = __builtin_amdgcn_mfma_f32_16x16x32_f16(ah[kt], read_w(Wsb, col, lg * 16 + kt * 64), acc, 0, 0, 0);
    acc8[t] = acc;
  }
  __syncthreads();
  stage_w((const char*)uWt, 512, 256, Wsb, tid, 8);    // ag-part (k 128..255)
  __syncthreads();
  #pragma unroll
  for (int t = 0; t < 8; ++t) {
    f32x4 acc = acc8[t];
    int col = t * 16 + lr;
    #pragma unroll
    for (int kt = 0; kt < 4; ++kt)
      acc = __builtin_amdgcn_mfma_f32_16x16x32_f16(aa[kt], read_w(Wsb, col, lg * 16 + kt * 64), acc, 0, 0, 0);
    float bias = ub[col];
    #pragma unroll
    for (int j = 0; j < 4; ++j) {
      f16 hv = (f16)tanh_fast(acc[j] + bias);
      int srow = w * 16 + lg * 4 + j;
      int byte = srow * 256 + (((col * 2) ^ ((srow & 7) << 4)));
      *reinterpret_cast<f16*>(Sb + byte) = hv;
      int grow = r0 + lg * 4 + j;
      if (grow < n) hout[(size_t)grow * ED + col] = hv;
    }
  }
  half8 ha[4];
  {
    int lrow = w * 16 + lr;
    #pragma unroll
    for (int kt = 0; kt < 4; ++kt) {
      int byte = lrow * 256 + ((lg * 16 + kt * 64) ^ ((lrow & 7) << 4));
      ha[kt] = *reinterpret_cast<const half8*>(Sb + byte);
    }
  }
  __syncthreads();

  // ---- phase M ----
  stage_w((const char*)mWt, 256, 0, Wsb, tid, 8);
  __syncthreads();
  #pragma unroll
  for (int t = 0; t < 8; ++t) {
    f32x4 acc = {0.f, 0.f, 0.f, 0.f};
    int col = t * 16 + lr;
    #pragma unroll
    for (int kt = 0; kt < 4; ++kt)
      acc = __builtin_amdgcn_mfma_f32_16x16x32_f16(ha[kt], read_w(Wsb, col, lg * 16 + kt * 64), acc, 0, 0, 0);
    float bias = mb[col];
    #pragma unroll
    for (int j = 0; j < 4; ++j) {
      int srow = w * 16 + lg * 4 + j;
      int byte = srow * 256 + (((col * 2) ^ ((srow & 7) << 4)));
      *reinterpret_cast<f16*>(Sb + byte) = (f16)tanh_fast(acc[j] + bias);
    }
  }
  half8 ma[4];
  {
    int lrow = w * 16 + lr;
    #pragma unroll
    for (int kt = 0; kt < 4; ++kt) {
      int byte = lrow * 256 + ((lg * 16 + kt * 64) ^ ((lrow & 7) << 4));
      ma[kt] = *reinterpret_cast<const half8*>(Sb + byte);
    }
  }
  __syncthreads();

  // ---- phase G ----
  stage_w((const char*)gWt, 256, 0, Wsb, tid, 8);
  __syncthreads();
  float wreg[8][4];
  #pragma unroll
  for (int t = 0; t < 8; ++t) {
    f32x4 acc = {0.f, 0.f, 0.f, 0.f};
    int col = t * 16 + lr;
    #pragma unroll
    for (int kt = 0; kt < 4; ++kt)
      acc = __builtin_amdgcn_mfma_f32_16x16x32_f16(ma[kt], read_w(Wsb, col, lg * 16 + kt * 64), acc, 0, 0, 0);
    float bias = gb[col];
    #pragma unroll
    for (int j = 0; j < 4; ++j) {
      float ww = fminf(__expf(acc[j] + bias), 60000.f);
      wreg[t][j] = ww;
      int grow = r0 + lg * 4 + j;
      if (grow < n) P[(size_t)grow * PROW + col] = (f16)ww;
    }
  }
  __syncthreads();

  // ---- phase V ----
  stage_w((const char*)aWt, 256, 0, Wsb, tid, 8);
  __syncthreads();
  #pragma unroll
  for (int t = 0; t < 8; ++t) {
    f32x4 acc = {0.f, 0.f, 0.f, 0.f};
    int col = t * 16 + lr;
    #pragma unroll
    for (int kt = 0; kt < 4; ++kt)
      acc = __builtin_amdgcn_mfma_f32_16x16x32_f16(ma[kt], read_w(Wsb, col, lg * 16 + kt * 64), acc, 0, 0, 0);
    float bias = ab[col];
    #pragma unroll
    for (int j = 0; j < 4; ++j) {
      int grow = r0 + lg * 4 + j;
      if (grow < n)
        P[(size_t)grow * PROW + 128 + col] = (f16)(wreg[t][j] * tanh_fast(acc[j] + bias));
    }
  }
}

// ---------------- fused upd + decoder (layer 2 end) ----------------
__global__ __launch_bounds__(256) void upddec_kernel(
    const f16* __restrict__ h, const f16* __restrict__ ag,
    const f16* __restrict__ uWt, const float* __restrict__ ub,
    const f16* __restrict__ d1Wt, const float* __restrict__ d1b,
    const float* __restrict__ d2W, const float* __restrict__ d2b,
    float* __restrict__ out, int n) {
  __shared__ f16 Ws[128 * 128];
  __shared__ f16 Ss[64 * 128];
  char* Wsb = reinterpret_cast<char*>(Ws);
  char* Sb = reinterpret_cast<char*>(Ss);
  const int tid = threadIdx.x;
  const int w = tid >> 6, lane = tid & 63;
  const int lr = lane & 15, lg = lane >> 4;
  const int r0 = blockIdx.x * 64 + w * 16;

  half8 ah[4], aa[4];
  {
    int rr = r0 + lr;
    if (rr >= n) rr = n - 1;
    const f16* ap = h + (size_t)rr * ED + lg * 8;
    const f16* bp = ag + (size_t)rr * ED + lg * 8;
    #pragma unroll
    for (int kt = 0; kt < 4; ++kt) {
      ah[kt] = *reinterpret_cast<const half8*>(ap + kt * 32);
      aa[kt] = *reinterpret_cast<const half8*>(bp + kt * 32);
    }
  }

  // ---- phase U (two halves) -> stripe only ----
  stage_w((const char*)uWt, 512, 0, Wsb, tid, 8);
  __syncthreads();
  f32x4 acc8[8];
  #pragma unroll
  for (int t = 0; t < 8; ++t) {
    f32x4 acc = {0.f, 0.f, 0.f, 0.f};
    int col = t * 16 + lr;
    #pragma unroll
    for (int kt = 0; kt < 4; ++kt)
      acc = __builtin_amdgcn_mfma_f32_16x16x32_f16(ah[kt], read_w(Wsb, col, lg * 16 + kt * 64), acc, 0, 0, 0);
    acc8[t] = acc;
  }
  __syncthreads();
  stage_w((const char*)uWt, 512, 256, Wsb, tid, 8);
  __syncthreads();
  #pragma unroll
  for (int t = 0; t < 8; ++t) {
    f32x4 acc = acc8[t];
    int col = t * 16 + lr;
    #pragma unroll
    for (int kt = 0; kt < 4; ++kt)
      acc = __builtin_amdgcn_mfma_f32_16x16x32_f16(aa[kt], read_w(Wsb, col, lg * 16 + kt * 64), acc, 0, 0, 0);
    float bias = ub[col];
    #pragma unroll
    for (int j = 0; j < 4; ++j) {
      int srow = w * 16 + lg * 4 + j;
      int byte = srow * 256 + (((col * 2) ^ ((srow & 7) << 4)));
      *reinterpret_cast<f16*>(Sb + byte) = (f16)tanh_fast(acc[j] + bias);
    }
  }
  half8 ha[4];
  {
    int lrow = w * 16 + lr;
    #pragma unroll
    for (int kt = 0; kt < 4; ++kt) {
      int byte = lrow * 256 + ((lg * 16 + kt * 64) ^ ((lrow & 7) << 4));
      ha[kt] = *reinterpret_cast<const half8*>(Sb + byte);
    }
  }
  __syncthreads();

  // ---- decoder: y = tanh(h3@d1W+d1b); out = y@d2W + d2b ----
  stage_w((const char*)d1Wt, 256, 0, Wsb, tid, 4);   // 64 cols x 128 k = 16 KB
  __syncthreads();
  float rowsum[4] = {0.f, 0.f, 0.f, 0.f};
  #pragma unroll
  for (int t = 0; t < 4; ++t) {
    f32x4 acc = {0.f, 0.f, 0.f, 0.f};
    int col = t * 16 + lr;
    #pragma unroll
    for (int kt = 0; kt < 4; ++kt)
      acc = __builtin_amdgcn_mfma_f32_16x16x32_f16(ha[kt], read_w(Wsb, col, lg * 16 + kt * 64), acc, 0, 0, 0);
    float b1 = d1b[col], w2 = d2W[col];
    #pragma unroll
    for (int j = 0; j < 4; ++j) rowsum[j] += tanh_fast(acc[j] + b1) * w2;
  }
  #pragma unroll
  for (int d = 1; d < 16; d <<= 1) {
    #pragma unroll
    for (int j = 0; j < 4; ++j) rowsum[j] += __shfl_xor(rowsum[j], d, 64);
  }
  if (lr == 0) {
    #pragma unroll
    for (int j = 0; j < 4; ++j) {
      int grow = r0 + lg * 4 + j;
      if (grow < n) out[grow] = rowsum[j] + d2b[0];
    }
  }
}

// ---------------- edge aggregation: one wave per dst node, pure gather-sum ---
__global__ __launch_bounds__(256) void edge_aggr_kernel(
    const int* __restrict__ offs, const int* __restrict__ ssrc,
    const f16* __restrict__ P, f16* __restrict__ aggr, int n) {
  int i = blockIdx.x * 4 + (threadIdx.x >> 6);
  if (i >= n) return;
  int lane = threadIdx.x & 63;
  int s0 = offs[i], s1 = offs[i + 1];
  const char* Pb = reinterpret_cast<const char*>(P);

  float4 acc = {0.f, 0.f, 0.f, 0.f};
  #pragma unroll 4
  for (int e = s0; e < s1; ++e) {
    int sn = ssrc[e];
    half4 x = *reinterpret_cast<const half4*>(Pb + (size_t)sn * 512 + lane * 8);
    acc.x += (float)x.x;
    acc.y += (float)x.y;
    acc.z += (float)x.z;
    acc.w += (float)x.w;
  }
  float px = __shfl(acc.x, lane ^ 32, 64);
  float py = __shfl(acc.y, lane ^ 32, 64);
  float pz = __shfl(acc.z, lane ^ 32, 64);
  float pw = __shfl(acc.w, lane ^ 32, 64);
  if (lane >= 32) {
    half4 o;
    o.x = (f16)(acc.x / (px + 1e-16f));
    o.y = (f16)(acc.y / (py + 1e-16f));
    o.z = (f16)(acc.z / (pz + 1e-16f));
    o.w = (f16)(acc.w / (pw + 1e-16f));
    *reinterpret_cast<half4*>(
        reinterpret_cast<char*>(aggr) + (size_t)i * 256 + (size_t)(lane - 32) * 8) = o;
  }
}

// ---------------- host ----------------
extern "C" void kernel_launch(void* const* d_in, const int* in_sizes, int n_in,
                              void* d_out, int out_size, void* d_ws, size_t ws_size,
                              hipStream_t stream) {
  const float* node_feature = (const float*)d_in[0];
  const int*   edge_index   = (const int*)d_in[1];
  const float* enc_W  = (const float*)d_in[3];
  const float* enc_b  = (const float*)d_in[4];
  const float* gate_W = (const float*)d_in[5];
  const float* gate_b = (const float*)d_in[6];
  const float* att_W  = (const float*)d_in[7];
  const float* att_b  = (const float*)d_in[8];
  const float* msg_W  = (const float*)d_in[9];
  const float* msg_b  = (const float*)d_in[10];
  const float* upd_W  = (const float*)d_in[11];
  const float* upd_b  = (const float*)d_in[12];
  const float* dec1_W = (const float*)d_in[13];
  const float* dec1_b = (const float*)d_in[14];
  const float* dec2_W = (const float*)d_in[15];
  const float* dec2_b = (const float*)d_in[16];

  const int n = in_sizes[0] / 2;   // 50000
  const int E = in_sizes[1] / 2;   // 800000
  const int* src = edge_index;
  const int* dst = edge_index + E;

  char* ws = (char*)d_ws;
  size_t off = 0;
  auto alloc = [&](size_t bytes) -> void* {
    void* p = ws + off;
    off += (bytes + 255) & ~(size_t)255;
    return p;
  };
  f16* hA   = (f16*)alloc((size_t)n * ED * 2);
  f16* hB   = (f16*)alloc((size_t)n * ED * 2);
  f16* P    = (f16*)alloc((size_t)n * PROW * 2);
  f16* aggr = (f16*)alloc((size_t)n * ED * 2);
  int* deg    = (int*)alloc((size_t)n * 4);
  int* offs   = (int*)alloc((size_t)(n + 1) * 4);
  int* cursor = (int*)alloc((size_t)n * 4);
  int* ssrc   = (int*)alloc((size_t)E * 4);
  f16* msgT  = (f16*)alloc((size_t)3 * ED * ED * 2);
  f16* gateT = (f16*)alloc((size_t)3 * ED * ED * 2);
  f16* attT  = (f16*)alloc((size_t)3 * ED * ED * 2);
  f16* updT  = (f16*)alloc((size_t)3 * ED * 2 * ED * 2);
  f16* dec1T = (f16*)alloc((size_t)ED * 64 * 2);

  // weight prep (once per call)
  {
    int tot3 = 3 * 3 * ED * ED;
    transpose3_kernel<<<(tot3 + 255) / 256, 256, 0, stream>>>(
        msg_W, gate_W, att_W, msgT, gateT, attT);
    int totu = 3 * 2 * ED * ED;
    transpose_w_kernel<<<(totu + 255) / 256, 256, 0, stream>>>(
        upd_W, updT, 2 * ED, ED, totu);
    int totd = ED * 64;
    transpose_w_kernel<<<(totd + 255) / 256, 256, 0, stream>>>(
        dec1_W, dec1T, ED, 64, totd);
  }

  // CSR build (once per call)
  hipMemsetAsync(deg, 0, (size_t)n * 4, stream);
  count_deg_kernel<<<(E + 255) / 256, 256, 0, stream>>>(dst, deg, E);
  scan_kernel<<<1, 1024, 0, stream>>>(deg, offs, cursor, n);
  scatter_kernel<<<(E + 255) / 256, 256, 0, stream>>>(src, dst, cursor, ssrc, E);

  // encoder
  encoder_kernel<<<((size_t)n * ED + 255) / 256, 256, 0, stream>>>(
      node_feature, enc_W, enc_b, hA, n);

  const int gemm_grid = (n + 63) / 64;   // 256-thread blocks, 64 rows
  const int aggr_grid = (n + 3) / 4;

  // layer 0 MGV
  gemm_mgv_kernel<<<gemm_grid, 256, 0, stream>>>(
      hA, msgT, msg_b, gateT, gate_b, attT, att_b, P, n);
  edge_aggr_kernel<<<aggr_grid, 256, 0, stream>>>(offs, ssrc, P, aggr, n);

  // upd0 + MGV1
  updmgv_kernel<<<gemm_grid, 256, 0, stream>>>(
      hA, aggr, updT, upd_b,
      msgT + (size_t)1 * ED * ED, msg_b + ED,
      gateT + (size_t)1 * ED * ED, gate_b + ED,
      attT + (size_t)1 * ED * ED, att_b + ED,
      hB, P, n);
  edge_aggr_kernel<<<aggr_grid, 256, 0, stream>>>(offs, ssrc, P, aggr, n);

  // upd1 + MGV2
  updmgv_kernel<<<gemm_grid, 256, 0, stream>>>(
      hB, aggr, updT + (size_t)1 * 2 * ED * ED, upd_b + ED,
      msgT + (size_t)2 * ED * ED, msg_b + 2 * ED,
      gateT + (size_t)2 * ED * ED, gate_b + 2 * ED,
      attT + (size_t)2 * ED * ED, att_b + 2 * ED,
      hA, P, n);
  edge_aggr_kernel<<<aggr_grid, 256, 0, stream>>>(offs, ssrc, P, aggr, n);

  // upd2 + decoder
  upddec_kernel<<<gemm_grid, 256, 0, stream>>>(
      hA, aggr, updT + (size_t)2 * 2 * ED * ED, upd_b + 2 * ED,
      dec1T, dec1_b, dec2_W, dec2_b, (float*)d_out, n);
}

// Round 11
// 463.692 us; speedup vs baseline: 1.2522x; 1.0073x over previous
//
#include <hip/hip_runtime.h>
#include <math.h>

#define ED 128
// packed per-node row: 128 f16 w=exp(gate) + 128 f16 wv=w*v  (512 B)
#define PROW 256

typedef _Float16 f16;
typedef _Float16 half8 __attribute__((ext_vector_type(8)));
typedef _Float16 half4 __attribute__((ext_vector_type(4)));
typedef float f32x4 __attribute__((ext_vector_type(4)));

// fast tanh: ~6 VALU ops via v_exp_f32; err ~1e-6
static __device__ __forceinline__ float tanh_fast(float x) {
  float ax = fabsf(x);
  float e = __expf(2.0f * ax);
  float t = 1.0f - 2.0f / (e + 1.0f);
  return __builtin_copysignf(t, x);
}

// ---- stage a [rows][rowBytes] f16 weight panel into swizzled LDS ----
static __device__ __forceinline__ void stage_w(
    const char* __restrict__ gsrc, int rowBytes, int rowOff,
    char* lds, int tid, int nIter) {
  #pragma unroll
  for (int i = 0; i < nIter; ++i) {
    int b = (i * 256 + tid) * 16;
    int row = b >> 8;
    int sw = (b & 255) ^ ((row & 7) << 4);
    float4 v = *reinterpret_cast<const float4*>(
        gsrc + (size_t)row * rowBytes + rowOff + sw);
    *reinterpret_cast<float4*>(lds + b) = v;
  }
}

static __device__ __forceinline__ half8 read_w(const char* Wsb, int col, int koff) {
  int byte = col * 256 + (koff ^ ((col & 7) << 4));
  return *reinterpret_cast<const half8*>(Wsb + byte);
}

// ---------------- encoder: h = tanh(x @ enc_W + enc_b) -> f16 ----------------
__global__ __launch_bounds__(256) void encoder_kernel(
    const float* __restrict__ x, const float* __restrict__ W,
    const float* __restrict__ b, f16* __restrict__ h, int n) {
  int idx = blockIdx.x * blockDim.x + threadIdx.x;
  if (idx >= n * ED) return;
  int i = idx >> 7, c = idx & 127;
  float v = x[i * 2 + 0] * W[c] + x[i * 2 + 1] * W[ED + c] + b[c];
  h[idx] = (f16)tanh_fast(v);
}

// ---------------- weight transpose+cast ----------------
__global__ __launch_bounds__(256) void transpose_w_kernel(
    const float* __restrict__ src, f16* __restrict__ dst, int K, int C, int total) {
  int idx = blockIdx.x * 256 + threadIdx.x;
  if (idx >= total) return;
  int kc = K * C;
  int m = idx / kc;
  int rem = idx - m * kc;
  int c = rem / K;
  int k = rem - c * K;
  dst[idx] = (f16)src[(size_t)m * kc + (size_t)k * C + c];
}

__global__ __launch_bounds__(256) void transpose3_kernel(
    const float* __restrict__ s0, const float* __restrict__ s1,
    const float* __restrict__ s2, f16* __restrict__ d0,
    f16* __restrict__ d1, f16* __restrict__ d2) {
  int idx = blockIdx.x * 256 + threadIdx.x;
  const int per = 3 * 128 * 128;
  int which = idx / per;
  if (which >= 3) return;
  int rem = idx - which * per;
  const float* s = (which == 0) ? s0 : (which == 1) ? s1 : s2;
  f16* d = (which == 0) ? d0 : (which == 1) ? d1 : d2;
  int m = rem >> 14;
  int r2 = rem & 16383;
  int c = r2 >> 7, k = r2 & 127;
  d[rem] = (f16)s[m * 16384 + k * 128 + c];
}

// ---------------- CSR build ----------------
__global__ __launch_bounds__(256) void count_deg_kernel(
    const int* __restrict__ dst, int* __restrict__ deg, int E) {
  int e = blockIdx.x * blockDim.x + threadIdx.x;
  if (e < E) atomicAdd(&deg[dst[e]], 1);
}

__global__ __launch_bounds__(1024) void scan_kernel(
    const int* __restrict__ deg, int* __restrict__ offs,
    int* __restrict__ cursor, int n) {
  __shared__ int wsum[16];
  __shared__ int carry_s;
  const int tid = threadIdx.x;
  const int lane = tid & 63;
  const int wid = tid >> 6;
  if (tid == 0) carry_s = 0;
  __syncthreads();
  for (int base = 0; base < n; base += 1024) {
    const int i = base + tid;
    const int v = (i < n) ? deg[i] : 0;
    int x = v;
    #pragma unroll
    for (int d = 1; d < 64; d <<= 1) {
      int t = __shfl_up(x, d, 64);
      if (lane >= d) x += t;
    }
    if (lane == 63) wsum[wid] = x;
    __syncthreads();
    int wbase = 0, total = 0;
    #pragma unroll
    for (int w = 0; w < 16; ++w) {
      int s = wsum[w];
      if (w < wid) wbase += s;
      total += s;
    }
    const int carry = carry_s;
    if (i < n) {
      const int excl = carry + wbase + x - v;
      offs[i] = excl;
      cursor[i] = excl;
    }
    __syncthreads();
    if (tid == 0) carry_s = carry + total;
    __syncthreads();
  }
  if (tid == 0) offs[n] = carry_s;
}

__global__ __launch_bounds__(256) void scatter_kernel(
    const int* __restrict__ src, const int* __restrict__ dst,
    int* __restrict__ cursor, int* __restrict__ ssrc, int E) {
  int e = blockIdx.x * blockDim.x + threadIdx.x;
  if (e < E) {
    int d = dst[e];
    int pos = atomicAdd(&cursor[d], 1);
    ssrc[pos] = src[e];
  }
}

// ==================== GEMM kernels: 256 thr = 4 waves x 16-row stripes,
// weights staged in swizzled LDS once per block per phase ====================

// ---------------- MGV layer 0 ----------------
__global__ __launch_bounds__(256) void gemm_mgv_kernel(
    const f16* __restrict__ h,
    const f16* __restrict__ mWt, const float* __restrict__ mb,
    const f16* __restrict__ gWt, const float* __restrict__ gb,
    const f16* __restrict__ aWt, const float* __restrict__ ab,
    f16* __restrict__ P, int n) {
  __shared__ f16 Ws[128 * 128];   // 32 KB weight panel
  __shared__ f16 Ss[64 * 128];    // 16 KB stripe buffer (M)
  char* Wsb = reinterpret_cast<char*>(Ws);
  char* Sb = reinterpret_cast<char*>(Ss);
  const int tid = threadIdx.x;
  const int w = tid >> 6, lane = tid & 63;
  const int lr = lane & 15, lg = lane >> 4;
  const int r0 = blockIdx.x * 64 + w * 16;

  half8 a[4];
  {
    int rr = r0 + lr;
    if (rr >= n) rr = n - 1;
    const f16* ap = h + (size_t)rr * ED + lg * 8;
    #pragma unroll
    for (int kt = 0; kt < 4; ++kt)
      a[kt] = *reinterpret_cast<const half8*>(ap + kt * 32);
  }

  // ---- phase M: M = tanh(h@mW+mb) -> stripe ----
  stage_w((const char*)mWt, 256, 0, Wsb, tid, 8);
  __syncthreads();
  #pragma unroll
  for (int t = 0; t < 8; ++t) {
    f32x4 acc = {0.f, 0.f, 0.f, 0.f};
    int col = t * 16 + lr;
    #pragma unroll
    for (int kt = 0; kt < 4; ++kt)
      acc = __builtin_amdgcn_mfma_f32_16x16x32_f16(a[kt], read_w(Wsb, col, lg * 16 + kt * 64), acc, 0, 0, 0);
    float bias = mb[col];
    #pragma unroll
    for (int j = 0; j < 4; ++j) {
      int srow = w * 16 + lg * 4 + j;
      int byte = srow * 256 + (((col * 2) ^ ((srow & 7) << 4)));
      *reinterpret_cast<f16*>(Sb + byte) = (f16)tanh_fast(acc[j] + bias);
    }
  }
  half8 ma[4];
  {
    int lrow = w * 16 + lr;
    #pragma unroll
    for (int kt = 0; kt < 4; ++kt) {
      int byte = lrow * 256 + ((lg * 16 + kt * 64) ^ ((lrow & 7) << 4));
      ma[kt] = *reinterpret_cast<const half8*>(Sb + byte);
    }
  }
  __syncthreads();

  // ---- phase G: w = exp(M@gW+gb) ----
  stage_w((const char*)gWt, 256, 0, Wsb, tid, 8);
  __syncthreads();
  float wreg[8][4];
  #pragma unroll
  for (int t = 0; t < 8; ++t) {
    f32x4 acc = {0.f, 0.f, 0.f, 0.f};
    int col = t * 16 + lr;
    #pragma unroll
    for (int kt = 0; kt < 4; ++kt)
      acc = __builtin_amdgcn_mfma_f32_16x16x32_f16(ma[kt], read_w(Wsb, col, lg * 16 + kt * 64), acc, 0, 0, 0);
    float bias = gb[col];
    #pragma unroll
    for (int j = 0; j < 4; ++j) {
      float ww = fminf(__expf(acc[j] + bias), 60000.f);
      wreg[t][j] = ww;
      int grow = r0 + lg * 4 + j;
      if (grow < n) P[(size_t)grow * PROW + col] = (f16)ww;
    }
  }
  __syncthreads();

  // ---- phase V: wv = w * tanh(M@aW+ab) ----
  stage_w((const char*)aWt, 256, 0, Wsb, tid, 8);
  __syncthreads();
  #pragma unroll
  for (int t = 0; t < 8; ++t) {
    f32x4 acc = {0.f, 0.f, 0.f, 0.f};
    int col = t * 16 + lr;
    #pragma unroll
    for (int kt = 0; kt < 4; ++kt)
      acc = __builtin_amdgcn_mfma_f32_16x16x32_f16(ma[kt], read_w(Wsb, col, lg * 16 + kt * 64), acc, 0, 0, 0);
    float bias = ab[col];
    #pragma unroll
    for (int j = 0; j < 4; ++j) {
      int grow = r0 + lg * 4 + j;
      if (grow < n)
        P[(size_t)grow * PROW + 128 + col] = (f16)(wreg[t][j] * tanh_fast(acc[j] + bias));
    }
  }
}

// ---------------- fused upd + MGV (layers 1,2) ----------------
__global__ __launch_bounds__(256) void updmgv_kernel(
    const f16* __restrict__ h, const f16* __restrict__ ag,
    const f16* __restrict__ uWt, const float* __restrict__ ub,
    const f16* __restrict__ mWt, const float* __restrict__ mb,
    const f16* __restrict__ gWt, const float* __restrict__ gb,
    const f16* __restrict__ aWt, const float* __restrict__ ab,
    f16* __restrict__ hout, f16* __restrict__ P, int n) {
  __shared__ f16 Ws[128 * 128];   // 32 KB weight panel
  __shared__ f16 Ss[64 * 128];    // 16 KB stripe buffer (h_new, then M)
  char* Wsb = reinterpret_cast<char*>(Ws);
  char* Sb = reinterpret_cast<char*>(Ss);
  const int tid = threadIdx.x;
  const int w = tid >> 6, lane = tid & 63;
  const int lr = lane & 15, lg = lane >> 4;
  const int r0 = blockIdx.x * 64 + w * 16;

  half8 ah[4], aa[4];
  {
    int rr = r0 + lr;
    if (rr >= n) rr = n - 1;
    const f16* ap = h + (size_t)rr * ED + lg * 8;
    const f16* bp = ag + (size_t)rr * ED + lg * 8;
    #pragma unroll
    for (int kt = 0; kt < 4; ++kt) {
      ah[kt] = *reinterpret_cast<const half8*>(ap + kt * 32);
      aa[kt] = *reinterpret_cast<const half8*>(bp + kt * 32);
    }
  }

  // ---- phase U: h_new = tanh([h,ag]@uW+ub), uW staged in two 32KB halves ----
  stage_w((const char*)uWt, 512, 0, Wsb, tid, 8);      // h-part (k 0..127)
  __syncthreads();
  f32x4 acc8[8];
  #pragma unroll
  for (int t = 0; t < 8; ++t) {
    f32x4 acc = {0.f, 0.f, 0.f, 0.f};
    int col = t * 16 + lr;
    #pragma unroll
    for (int kt = 0; kt < 4; ++kt)
      acc = __builtin_amdgcn_mfma_f32_16x16x32_f16(ah[kt], read_w(Wsb, col, lg * 16 + kt * 64), acc, 0, 0, 0);
    acc8[t] = acc;
  }
  __syncthreads();
  stage_w((const char*)uWt, 512, 256, Wsb, tid, 8);    // ag-part (k 128..255)
  __syncthreads();
  #pragma unroll
  for (int t = 0; t < 8; ++t) {
    f32x4 acc = acc8[t];
    int col = t * 16 + lr;
    #pragma unroll
    for (int kt = 0; kt < 4; ++kt)
      acc = __builtin_amdgcn_mfma_f32_16x16x32_f16(aa[kt], read_w(Wsb, col, lg * 16 + kt * 64), acc, 0, 0, 0);
    float bias = ub[col];
    #pragma unroll
    for (int j = 0; j < 4; ++j) {
      f16 hv = (f16)tanh_fast(acc[j] + bias);
      int srow = w * 16 + lg * 4 + j;
      int byte = srow * 256 + (((col * 2) ^ ((srow & 7) << 4)));
      *reinterpret_cast<f16*>(Sb + byte) = hv;
      int grow = r0 + lg * 4 + j;
      if (grow < n) hout[(size_t)grow * ED + col] = hv;
    }
  }
  half8 ha[4];
  {
    int lrow = w * 16 + lr;
    #pragma unroll
    for (int kt = 0; kt < 4; ++kt) {
      int byte = lrow * 256 + ((lg * 16 + kt * 64) ^ ((lrow & 7) << 4));
      ha[kt] = *reinterpret_cast<const half8*>(Sb + byte);
    }
  }
  __syncthreads();

  // ---- phase M ----
  stage_w((const char*)mWt, 256, 0, Wsb, tid, 8);
  __syncthreads();
  #pragma unroll
  for (int t = 0; t < 8; ++t) {
    f32x4 acc = {0.f, 0.f, 0.f, 0.f};
    int col = t * 16 + lr;
    #pragma unroll
    for (int kt = 0; kt < 4; ++kt)
      acc = __builtin_amdgcn_mfma_f32_16x16x32_f16(ha[kt], read_w(Wsb, col, lg * 16 + kt * 64), acc, 0, 0, 0);
    float bias = mb[col];
    #pragma unroll
    for (int j = 0; j < 4; ++j) {
      int srow = w * 16 + lg * 4 + j;
      int byte = srow * 256 + (((col * 2) ^ ((srow & 7) << 4)));
      *reinterpret_cast<f16*>(Sb + byte) = (f16)tanh_fast(acc[j] + bias);
    }
  }
  half8 ma[4];
  {
    int lrow = w * 16 + lr;
    #pragma unroll
    for (int kt = 0; kt < 4; ++kt) {
      int byte = lrow * 256 + ((lg * 16 + kt * 64) ^ ((lrow & 7) << 4));
      ma[kt] = *reinterpret_cast<const half8*>(Sb + byte);
    }
  }
  __syncthreads();

  // ---- phase G ----
  stage_w((const char*)gWt, 256, 0, Wsb, tid, 8);
  __syncthreads();
  float wreg[8][4];
  #pragma unroll
  for (int t = 0; t < 8; ++t) {
    f32x4 acc = {0.f, 0.f, 0.f, 0.f};
    int col = t * 16 + lr;
    #pragma unroll
    for (int kt = 0; kt < 4; ++kt)
      acc = __builtin_amdgcn_mfma_f32_16x16x32_f16(ma[kt], read_w(Wsb, col, lg * 16 + kt * 64), acc, 0, 0, 0);
    float bias = gb[col];
    #pragma unroll
    for (int j = 0; j < 4; ++j) {
      float ww = fminf(__expf(acc[j] + bias), 60000.f);
      wreg[t][j] = ww;
      int grow = r0 + lg * 4 + j;
      if (grow < n) P[(size_t)grow * PROW + col] = (f16)ww;
    }
  }
  __syncthreads();

  // ---- phase V ----
  stage_w((const char*)aWt, 256, 0, Wsb, tid, 8);
  __syncthreads();
  #pragma unroll
  for (int t = 0; t < 8; ++t) {
    f32x4 acc = {0.f, 0.f, 0.f, 0.f};
    int col = t * 16 + lr;
    #pragma unroll
    for (int kt = 0; kt < 4; ++kt)
      acc = __builtin_amdgcn_mfma_f32_16x16x32_f16(ma[kt], read_w(Wsb, col, lg * 16 + kt * 64), acc, 0, 0, 0);
    float bias = ab[col];
    #pragma unroll
    for (int j = 0; j < 4; ++j) {
      int grow = r0 + lg * 4 + j;
      if (grow < n)
        P[(size_t)grow * PROW + 128 + col] = (f16)(wreg[t][j] * tanh_fast(acc[j] + bias));
    }
  }
}

// ---------------- fused upd + decoder (layer 2 end) ----------------
__global__ __launch_bounds__(256) void upddec_kernel(
    const f16* __restrict__ h, const f16* __restrict__ ag,
    const f16* __restrict__ uWt, const float* __restrict__ ub,
    const f16* __restrict__ d1Wt, const float* __restrict__ d1b,
    const float* __restrict__ d2W, const float* __restrict__ d2b,
    float* __restrict__ out, int n) {
  __shared__ f16 Ws[128 * 128];
  __shared__ f16 Ss[64 * 128];
  char* Wsb = reinterpret_cast<char*>(Ws);
  char* Sb = reinterpret_cast<char*>(Ss);
  const int tid = threadIdx.x;
  const int w = tid >> 6, lane = tid & 63;
  const int lr = lane & 15, lg = lane >> 4;
  const int r0 = blockIdx.x * 64 + w * 16;

  half8 ah[4], aa[4];
  {
    int rr = r0 + lr;
    if (rr >= n) rr = n - 1;
    const f16* ap = h + (size_t)rr * ED + lg * 8;
    const f16* bp = ag + (size_t)rr * ED + lg * 8;
    #pragma unroll
    for (int kt = 0; kt < 4; ++kt) {
      ah[kt] = *reinterpret_cast<const half8*>(ap + kt * 32);
      aa[kt] = *reinterpret_cast<const half8*>(bp + kt * 32);
    }
  }

  // ---- phase U (two halves) -> stripe only ----
  stage_w((const char*)uWt, 512, 0, Wsb, tid, 8);
  __syncthreads();
  f32x4 acc8[8];
  #pragma unroll
  for (int t = 0; t < 8; ++t) {
    f32x4 acc = {0.f, 0.f, 0.f, 0.f};
    int col = t * 16 + lr;
    #pragma unroll
    for (int kt = 0; kt < 4; ++kt)
      acc = __builtin_amdgcn_mfma_f32_16x16x32_f16(ah[kt], read_w(Wsb, col, lg * 16 + kt * 64), acc, 0, 0, 0);
    acc8[t] = acc;
  }
  __syncthreads();
  stage_w((const char*)uWt, 512, 256, Wsb, tid, 8);
  __syncthreads();
  #pragma unroll
  for (int t = 0; t < 8; ++t) {
    f32x4 acc = acc8[t];
    int col = t * 16 + lr;
    #pragma unroll
    for (int kt = 0; kt < 4; ++kt)
      acc = __builtin_amdgcn_mfma_f32_16x16x32_f16(aa[kt], read_w(Wsb, col, lg * 16 + kt * 64), acc, 0, 0, 0);
    float bias = ub[col];
    #pragma unroll
    for (int j = 0; j < 4; ++j) {
      int srow = w * 16 + lg * 4 + j;
      int byte = srow * 256 + (((col * 2) ^ ((srow & 7) << 4)));
      *reinterpret_cast<f16*>(Sb + byte) = (f16)tanh_fast(acc[j] + bias);
    }
  }
  half8 ha[4];
  {
    int lrow = w * 16 + lr;
    #pragma unroll
    for (int kt = 0; kt < 4; ++kt) {
      int byte = lrow * 256 + ((lg * 16 + kt * 64) ^ ((lrow & 7) << 4));
      ha[kt] = *reinterpret_cast<const half8*>(Sb + byte);
    }
  }
  __syncthreads();

  // ---- decoder: y = tanh(h3@d1W+d1b); out = y@d2W + d2b ----
  stage_w((const char*)d1Wt, 256, 0, Wsb, tid, 4);   // 64 cols x 128 k = 16 KB
  __syncthreads();
  float rowsum[4] = {0.f, 0.f, 0.f, 0.f};
  #pragma unroll
  for (int t = 0; t < 4; ++t) {
    f32x4 acc = {0.f, 0.f, 0.f, 0.f};
    int col = t * 16 + lr;
    #pragma unroll
    for (int kt = 0; kt < 4; ++kt)
      acc = __builtin_amdgcn_mfma_f32_16x16x32_f16(ha[kt], read_w(Wsb, col, lg * 16 + kt * 64), acc, 0, 0, 0);
    float b1 = d1b[col], w2 = d2W[col];
    #pragma unroll
    for (int j = 0; j < 4; ++j) rowsum[j] += tanh_fast(acc[j] + b1) * w2;
  }
  #pragma unroll
  for (int d = 1; d < 16; d <<= 1) {
    #pragma unroll
    for (int j = 0; j < 4; ++j) rowsum[j] += __shfl_xor(rowsum[j], d, 64);
  }
  if (lr == 0) {
    #pragma unroll
    for (int j = 0; j < 4; ++j) {
      int grow = r0 + lg * 4 + j;
      if (grow < n) out[grow] = rowsum[j] + d2b[0];
    }
  }
}

// ---------------- edge aggregation: one wave per dst node, 8-deep pipelined --
__global__ __launch_bounds__(256) void edge_aggr_kernel(
    const int* __restrict__ offs, const int* __restrict__ ssrc,
    const f16* __restrict__ P, f16* __restrict__ aggr, int n) {
  int i = blockIdx.x * 4 + (threadIdx.x >> 6);
  if (i >= n) return;
  int lane = threadIdx.x & 63;
  int s0 = offs[i], s1 = offs[i + 1];
  const char* Pb = reinterpret_cast<const char*>(P);
  const size_t loff = (size_t)lane * 8;

  float4 acc = {0.f, 0.f, 0.f, 0.f};
  int e = s0;
  // 8-deep batch: 8 index loads, then 8 independent row loads in flight
  for (; e + 8 <= s1; e += 8) {
    int sn[8];
    #pragma unroll
    for (int q = 0; q < 8; ++q) sn[q] = ssrc[e + q];
    half4 x[8];
    #pragma unroll
    for (int q = 0; q < 8; ++q)
      x[q] = *reinterpret_cast<const half4*>(Pb + (size_t)sn[q] * 512 + loff);
    #pragma unroll
    for (int q = 0; q < 8; ++q) {
      acc.x += (float)x[q].x;
      acc.y += (float)x[q].y;
      acc.z += (float)x[q].z;
      acc.w += (float)x[q].w;
    }
  }
  for (; e < s1; ++e) {
    int sn = ssrc[e];
    half4 x = *reinterpret_cast<const half4*>(Pb + (size_t)sn * 512 + loff);
    acc.x += (float)x.x;
    acc.y += (float)x.y;
    acc.z += (float)x.z;
    acc.w += (float)x.w;
  }

  float px = __shfl(acc.x, lane ^ 32, 64);
  float py = __shfl(acc.y, lane ^ 32, 64);
  float pz = __shfl(acc.z, lane ^ 32, 64);
  float pw = __shfl(acc.w, lane ^ 32, 64);
  if (lane >= 32) {
    half4 o;
    o.x = (f16)(acc.x / (px + 1e-16f));
    o.y = (f16)(acc.y / (py + 1e-16f));
    o.z = (f16)(acc.z / (pz + 1e-16f));
    o.w = (f16)(acc.w / (pw + 1e-16f));
    *reinterpret_cast<half4*>(
        reinterpret_cast<char*>(aggr) + (size_t)i * 256 + (size_t)(lane - 32) * 8) = o;
  }
}

// ---------------- host ----------------
extern "C" void kernel_launch(void* const* d_in, const int* in_sizes, int n_in,
                              void* d_out, int out_size, void* d_ws, size_t ws_size,
                              hipStream_t stream) {
  const float* node_feature = (const float*)d_in[0];
  const int*   edge_index   = (const int*)d_in[1];
  const float* enc_W  = (const float*)d_in[3];
  const float* enc_b  = (const float*)d_in[4];
  const float* gate_W = (const float*)d_in[5];
  const float* gate_b = (const float*)d_in[6];
  const float* att_W  = (const float*)d_in[7];
  const float* att_b  = (const float*)d_in[8];
  const float* msg_W  = (const float*)d_in[9];
  const float* msg_b  = (const float*)d_in[10];
  const float* upd_W  = (const float*)d_in[11];
  const float* upd_b  = (const float*)d_in[12];
  const float* dec1_W = (const float*)d_in[13];
  const float* dec1_b = (const float*)d_in[14];
  const float* dec2_W = (const float*)d_in[15];
  const float* dec2_b = (const float*)d_in[16];

  const int n = in_sizes[0] / 2;   // 50000
  const int E = in_sizes[1] / 2;   // 800000
  const int* src = edge_index;
  const int* dst = edge_index + E;

  char* ws = (char*)d_ws;
  size_t off = 0;
  auto alloc = [&](size_t bytes) -> void* {
    void* p = ws + off;
    off += (bytes + 255) & ~(size_t)255;
    return p;
  };
  f16* hA   = (f16*)alloc((size_t)n * ED * 2);
  f16* hB   = (f16*)alloc((size_t)n * ED * 2);
  f16* P    = (f16*)alloc((size_t)n * PROW * 2);
  f16* aggr = (f16*)alloc((size_t)n * ED * 2);
  int* deg    = (int*)alloc((size_t)n * 4);
  int* offs   = (int*)alloc((size_t)(n + 1) * 4);
  int* cursor = (int*)alloc((size_t)n * 4);
  int* ssrc   = (int*)alloc((size_t)E * 4);
  f16* msgT  = (f16*)alloc((size_t)3 * ED * ED * 2);
  f16* gateT = (f16*)alloc((size_t)3 * ED * ED * 2);
  f16* attT  = (f16*)alloc((size_t)3 * ED * ED * 2);
  f16* updT  = (f16*)alloc((size_t)3 * ED * 2 * ED * 2);
  f16* dec1T = (f16*)alloc((size_t)ED * 64 * 2);

  // weight prep (once per call)
  {
    int tot3 = 3 * 3 * ED * ED;
    transpose3_kernel<<<(tot3 + 255) / 256, 256, 0, stream>>>(
        msg_W, gate_W, att_W, msgT, gateT, attT);
    int totu = 3 * 2 * ED * ED;
    transpose_w_kernel<<<(totu + 255) / 256, 256, 0, stream>>>(
        upd_W, updT, 2 * ED, ED, totu);
    int totd = ED * 64;
    transpose_w_kernel<<<(totd + 255) / 256, 256, 0, stream>>>(
        dec1_W, dec1T, ED, 64, totd);
  }

  // CSR build (once per call)
  hipMemsetAsync(deg, 0, (size_t)n * 4, stream);
  count_deg_kernel<<<(E + 255) / 256, 256, 0, stream>>>(dst, deg, E);
  scan_kernel<<<1, 1024, 0, stream>>>(deg, offs, cursor, n);
  scatter_kernel<<<(E + 255) / 256, 256, 0, stream>>>(src, dst, cursor, ssrc, E);

  // encoder
  encoder_kernel<<<((size_t)n * ED + 255) / 256, 256, 0, stream>>>(
      node_feature, enc_W, enc_b, hA, n);

  const int gemm_grid = (n + 63) / 64;   // 256-thread blocks, 64 rows
  const int aggr_grid = (n + 3) / 4;

  // layer 0 MGV
  gemm_mgv_kernel<<<gemm_grid, 256, 0, stream>>>(
      hA, msgT, msg_b, gateT, gate_b, attT, att_b, P, n);
  edge_aggr_kernel<<<aggr_grid, 256, 0, stream>>>(offs, ssrc, P, aggr, n);

  // upd0 + MGV1
  updmgv_kernel<<<gemm_grid, 256, 0, stream>>>(
      hA, aggr, updT, upd_b,
      msgT + (size_t)1 * ED * ED, msg_b + ED,
      gateT + (size_t)1 * ED * ED, gate_b + ED,
      attT + (size_t)1 * ED * ED, att_b + ED,
      hB, P, n);
  edge_aggr_kernel<<<aggr_grid, 256, 0, stream>>>(offs, ssrc, P, aggr, n);

  // upd1 + MGV2
  updmgv_kernel<<<gemm_grid, 256, 0, stream>>>(
      hB, aggr, updT + (size_t)1 * 2 * ED * ED, upd_b + ED,
      msgT + (size_t)2 * ED * ED, msg_b + 2 * ED,
      gateT + (size_t)2 * ED * ED, gate_b + 2 * ED,
      attT + (size_t)2 * ED * ED, att_b + 2 * ED,
      hA, P, n);
  edge_aggr_kernel<<<aggr_grid, 256, 0, stream>>>(offs, ssrc, P, aggr, n);

  // upd2 + decoder
  upddec_kernel<<<gemm_grid, 256, 0, stream>>>(
      hA, aggr, updT + (size_t)2 * 2 * ED * ED, upd_b + 2 * ED,
      dec1T, dec1_b, dec2_W, dec2_b, (float*)d_out, n);
}

// Round 12
// 442.551 us; speedup vs baseline: 1.3120x; 1.0478x over previous
//
#include <hip/hip_runtime.h>
#include <math.h>

#define ED 128
// packed per-node row: 128 f16 w=exp(gate) + 128 f16 wv=w*v  (512 B)
#define PROW 256

typedef _Float16 f16;
typedef _Float16 half8 __attribute__((ext_vector_type(8)));
typedef _Float16 half4 __attribute__((ext_vector_type(4)));
typedef float f32x4 __attribute__((ext_vector_type(4)));

// fast tanh: ~6 VALU ops via v_exp_f32; err ~1e-6
static __device__ __forceinline__ float tanh_fast(float x) {
  float ax = fabsf(x);
  float e = __expf(2.0f * ax);
  float t = 1.0f - 2.0f / (e + 1.0f);
  return __builtin_copysignf(t, x);
}

// ---- stage a [rows][256B] f16 weight panel into swizzled LDS ----
template <int NT, int NBYTES>
static __device__ __forceinline__ void stage256(
    const char* __restrict__ gsrc, char* lds, int tid) {
  #pragma unroll
  for (int i = 0; i < NBYTES / (NT * 16); ++i) {
    int b = (i * NT + tid) * 16;
    int row = b >> 8;
    int sw = (b & 255) ^ ((row & 7) << 4);
    float4 v = *reinterpret_cast<const float4*>(gsrc + (size_t)row * 256 + sw);
    *reinterpret_cast<float4*>(lds + b) = v;
  }
}

static __device__ __forceinline__ half8 read_w(const char* Wsb, int col, int koff) {
  int byte = col * 256 + (koff ^ ((col & 7) << 4));
  return *reinterpret_cast<const half8*>(Wsb + byte);
}

// ---- stage a [64 rows][512B] panel (uW col-half) into swizzled LDS ----
template <int NT>
static __device__ __forceinline__ void stage512(
    const char* __restrict__ gsrc, char* lds, int tid) {
  #pragma unroll
  for (int i = 0; i < 32768 / (NT * 16); ++i) {
    int b = (i * NT + tid) * 16;
    int row = b >> 9;
    int sw = (b & 511) ^ ((row & 7) << 4);
    float4 v = *reinterpret_cast<const float4*>(gsrc + (size_t)row * 512 + sw);
    *reinterpret_cast<float4*>(lds + b) = v;
  }
}

static __device__ __forceinline__ half8 read_w512(const char* Wsb, int colL, int koff) {
  int byte = colL * 512 + (koff ^ ((colL & 7) << 4));
  return *reinterpret_cast<const half8*>(Wsb + byte);
}

// ---------------- encoder: h = tanh(x @ enc_W + enc_b) -> f16 ----------------
__global__ __launch_bounds__(256) void encoder_kernel(
    const float* __restrict__ x, const float* __restrict__ W,
    const float* __restrict__ b, f16* __restrict__ h, int n) {
  int idx = blockIdx.x * blockDim.x + threadIdx.x;
  if (idx >= n * ED) return;
  int i = idx >> 7, c = idx & 127;
  float v = x[i * 2 + 0] * W[c] + x[i * 2 + 1] * W[ED + c] + b[c];
  h[idx] = (f16)tanh_fast(v);
}

// ---------------- weight transpose+cast ----------------
__global__ __launch_bounds__(256) void transpose_w_kernel(
    const float* __restrict__ src, f16* __restrict__ dst, int K, int C, int total) {
  int idx = blockIdx.x * 256 + threadIdx.x;
  if (idx >= total) return;
  int kc = K * C;
  int m = idx / kc;
  int rem = idx - m * kc;
  int c = rem / K;
  int k = rem - c * K;
  dst[idx] = (f16)src[(size_t)m * kc + (size_t)k * C + c];
}

__global__ __launch_bounds__(256) void transpose3_kernel(
    const float* __restrict__ s0, const float* __restrict__ s1,
    const float* __restrict__ s2, f16* __restrict__ d0,
    f16* __restrict__ d1, f16* __restrict__ d2) {
  int idx = blockIdx.x * 256 + threadIdx.x;
  const int per = 3 * 128 * 128;
  int which = idx / per;
  if (which >= 3) return;
  int rem = idx - which * per;
  const float* s = (which == 0) ? s0 : (which == 1) ? s1 : s2;
  f16* d = (which == 0) ? d0 : (which == 1) ? d1 : d2;
  int m = rem >> 14;
  int r2 = rem & 16383;
  int c = r2 >> 7, k = r2 & 127;
  d[rem] = (f16)s[m * 16384 + k * 128 + c];
}

// ---------------- CSR build ----------------
__global__ __launch_bounds__(256) void count_deg_kernel(
    const int* __restrict__ dst, int* __restrict__ deg, int E) {
  int e = blockIdx.x * blockDim.x + threadIdx.x;
  if (e < E) atomicAdd(&deg[dst[e]], 1);
}

__global__ __launch_bounds__(1024) void scan_kernel(
    const int* __restrict__ deg, int* __restrict__ offs,
    int* __restrict__ cursor, int n) {
  __shared__ int wsum[16];
  __shared__ int carry_s;
  const int tid = threadIdx.x;
  const int lane = tid & 63;
  const int wid = tid >> 6;
  if (tid == 0) carry_s = 0;
  __syncthreads();
  for (int base = 0; base < n; base += 1024) {
    const int i = base + tid;
    const int v = (i < n) ? deg[i] : 0;
    int x = v;
    #pragma unroll
    for (int d = 1; d < 64; d <<= 1) {
      int t = __shfl_up(x, d, 64);
      if (lane >= d) x += t;
    }
    if (lane == 63) wsum[wid] = x;
    __syncthreads();
    int wbase = 0, total = 0;
    #pragma unroll
    for (int w = 0; w < 16; ++w) {
      int s = wsum[w];
      if (w < wid) wbase += s;
      total += s;
    }
    const int carry = carry_s;
    if (i < n) {
      const int excl = carry + wbase + x - v;
      offs[i] = excl;
      cursor[i] = excl;
    }
    __syncthreads();
    if (tid == 0) carry_s = carry + total;
    __syncthreads();
  }
  if (tid == 0) offs[n] = carry_s;
}

__global__ __launch_bounds__(256) void scatter_kernel(
    const int* __restrict__ src, const int* __restrict__ dst,
    int* __restrict__ cursor, int* __restrict__ ssrc, int E) {
  int e = blockIdx.x * blockDim.x + threadIdx.x;
  if (e < E) {
    int d = dst[e];
    int pos = atomicAdd(&cursor[d], 1);
    ssrc[pos] = src[e];
  }
}

// ==================== GEMM kernels: 512 thr = 8 waves x 16-row stripes,
// 128 rows/block (grid 391, one co-resident round), weights staged in
// swizzled LDS once per block per phase. LDS 64 KB -> 2 blocks/CU. =========

// ---------------- MGV layer 0 ----------------
__global__ __launch_bounds__(512, 4) void gemm_mgv_kernel(
    const f16* __restrict__ h,
    const f16* __restrict__ mWt, const float* __restrict__ mb,
    const f16* __restrict__ gWt, const float* __restrict__ gb,
    const f16* __restrict__ aWt, const float* __restrict__ ab,
    f16* __restrict__ P, int n) {
  __shared__ f16 Ws[128 * 128];   // 32 KB weight panel
  __shared__ f16 Ss[128 * 128];   // 32 KB stripe buffer (M)
  char* Wsb = reinterpret_cast<char*>(Ws);
  char* Sb = reinterpret_cast<char*>(Ss);
  const int tid = threadIdx.x;
  const int w = tid >> 6, lane = tid & 63;
  const int lr = lane & 15, lg = lane >> 4;
  const int r0 = blockIdx.x * 128 + w * 16;

  half8 a[4];
  {
    int rr = r0 + lr;
    if (rr >= n) rr = n - 1;
    const f16* ap = h + (size_t)rr * ED + lg * 8;
    #pragma unroll
    for (int kt = 0; kt < 4; ++kt)
      a[kt] = *reinterpret_cast<const half8*>(ap + kt * 32);
  }

  // ---- phase M: M = tanh(h@mW+mb) -> stripe ----
  stage256<512, 32768>((const char*)mWt, Wsb, tid);
  __syncthreads();
  #pragma unroll
  for (int t = 0; t < 8; ++t) {
    f32x4 acc = {0.f, 0.f, 0.f, 0.f};
    int col = t * 16 + lr;
    #pragma unroll
    for (int kt = 0; kt < 4; ++kt)
      acc = __builtin_amdgcn_mfma_f32_16x16x32_f16(a[kt], read_w(Wsb, col, lg * 16 + kt * 64), acc, 0, 0, 0);
    float bias = mb[col];
    #pragma unroll
    for (int j = 0; j < 4; ++j) {
      int srow = w * 16 + lg * 4 + j;
      int byte = srow * 256 + (((col * 2) ^ ((srow & 7) << 4)));
      *reinterpret_cast<f16*>(Sb + byte) = (f16)tanh_fast(acc[j] + bias);
    }
  }
  half8 ma[4];   // wave-local stripe read (own rows) — no barrier needed
  {
    int lrow = w * 16 + lr;
    #pragma unroll
    for (int kt = 0; kt < 4; ++kt) {
      int byte = lrow * 256 + ((lg * 16 + kt * 64) ^ ((lrow & 7) << 4));
      ma[kt] = *reinterpret_cast<const half8*>(Sb + byte);
    }
  }
  __syncthreads();

  // ---- phase G: w = exp(M@gW+gb) -> P ----
  stage256<512, 32768>((const char*)gWt, Wsb, tid);
  __syncthreads();
  #pragma unroll
  for (int t = 0; t < 8; ++t) {
    f32x4 acc = {0.f, 0.f, 0.f, 0.f};
    int col = t * 16 + lr;
    #pragma unroll
    for (int kt = 0; kt < 4; ++kt)
      acc = __builtin_amdgcn_mfma_f32_16x16x32_f16(ma[kt], read_w(Wsb, col, lg * 16 + kt * 64), acc, 0, 0, 0);
    float bias = gb[col];
    #pragma unroll
    for (int j = 0; j < 4; ++j) {
      int grow = r0 + lg * 4 + j;
      if (grow < n)
        P[(size_t)grow * PROW + col] = (f16)fminf(__expf(acc[j] + bias), 60000.f);
    }
  }
  __syncthreads();

  // ---- phase V: wv = w * tanh(M@aW+ab); w re-read from P (same thread wrote it)
  stage256<512, 32768>((const char*)aWt, Wsb, tid);
  __syncthreads();
  #pragma unroll
  for (int t = 0; t < 8; ++t) {
    f32x4 acc = {0.f, 0.f, 0.f, 0.f};
    int col = t * 16 + lr;
    #pragma unroll
    for (int kt = 0; kt < 4; ++kt)
      acc = __builtin_amdgcn_mfma_f32_16x16x32_f16(ma[kt], read_w(Wsb, col, lg * 16 + kt * 64), acc, 0, 0, 0);
    float bias = ab[col];
    #pragma unroll
    for (int j = 0; j < 4; ++j) {
      int grow = r0 + lg * 4 + j;
      if (grow < n) {
        float wld = (float)P[(size_t)grow * PROW + col];
        P[(size_t)grow * PROW + 128 + col] = (f16)(wld * tanh_fast(acc[j] + bias));
      }
    }
  }
}

// ---------------- fused upd + MGV (layers 1,2) ----------------
__global__ __launch_bounds__(512, 4) void updmgv_kernel(
    const f16* __restrict__ h, const f16* __restrict__ ag,
    const f16* __restrict__ uWt, const float* __restrict__ ub,
    const f16* __restrict__ mWt, const float* __restrict__ mb,
    const f16* __restrict__ gWt, const float* __restrict__ gb,
    const f16* __restrict__ aWt, const float* __restrict__ ab,
    f16* __restrict__ hout, f16* __restrict__ P, int n) {
  __shared__ f16 Ws[128 * 128];   // 32 KB weight panel
  __shared__ f16 Ss[128 * 128];   // 32 KB stripe buffer (h_new, then M)
  char* Wsb = reinterpret_cast<char*>(Ws);
  char* Sb = reinterpret_cast<char*>(Ss);
  const int tid = threadIdx.x;
  const int w = tid >> 6, lane = tid & 63;
  const int lr = lane & 15, lg = lane >> 4;
  const int r0 = blockIdx.x * 128 + w * 16;

  half8 ah[4], aa[4];
  {
    int rr = r0 + lr;
    if (rr >= n) rr = n - 1;
    const f16* ap = h + (size_t)rr * ED + lg * 8;
    const f16* bp = ag + (size_t)rr * ED + lg * 8;
    #pragma unroll
    for (int kt = 0; kt < 4; ++kt) {
      ah[kt] = *reinterpret_cast<const half8*>(ap + kt * 32);
      aa[kt] = *reinterpret_cast<const half8*>(bp + kt * 32);
    }
  }

  // ---- phase U: h_new = tanh([h,ag]@uW+ub), split by COLUMN halves ----
  // each half stages 64 cols x 256 k (32 KB, 512-B LDS rows); full K per tile
  #pragma unroll
  for (int half = 0; half < 2; ++half) {
    __syncthreads();   // prior readers of Ws done (no-op on first iter)
    stage512<512>((const char*)uWt + (size_t)half * 64 * 512, Wsb, tid);
    __syncthreads();
    #pragma unroll
    for (int t = 0; t < 4; ++t) {
      int colL = t * 16 + lr;
      int col = half * 64 + colL;
      f32x4 acc = {0.f, 0.f, 0.f, 0.f};
      #pragma unroll
      for (int kt = 0; kt < 4; ++kt)
        acc = __builtin_amdgcn_mfma_f32_16x16x32_f16(ah[kt], read_w512(Wsb, colL, lg * 16 + kt * 64), acc, 0, 0, 0);
      #pragma unroll
      for (int kt = 0; kt < 4; ++kt)
        acc = __builtin_amdgcn_mfma_f32_16x16x32_f16(aa[kt], read_w512(Wsb, colL, 256 + lg * 16 + kt * 64), acc, 0, 0, 0);
      float bias = ub[col];
      #pragma unroll
      for (int j = 0; j < 4; ++j) {
        f16 hv = (f16)tanh_fast(acc[j] + bias);
        int srow = w * 16 + lg * 4 + j;
        int byte = srow * 256 + (((col * 2) ^ ((srow & 7) << 4)));
        *reinterpret_cast<f16*>(Sb + byte) = hv;
        int grow = r0 + lg * 4 + j;
        if (grow < n) hout[(size_t)grow * ED + col] = hv;
      }
    }
  }
  half8 ha[4];   // wave-local stripe read
  {
    int lrow = w * 16 + lr;
    #pragma unroll
    for (int kt = 0; kt < 4; ++kt) {
      int byte = lrow * 256 + ((lg * 16 + kt * 64) ^ ((lrow & 7) << 4));
      ha[kt] = *reinterpret_cast<const half8*>(Sb + byte);
    }
  }
  __syncthreads();

  // ---- phase M ----
  stage256<512, 32768>((const char*)mWt, Wsb, tid);
  __syncthreads();
  #pragma unroll
  for (int t = 0; t < 8; ++t) {
    f32x4 acc = {0.f, 0.f, 0.f, 0.f};
    int col = t * 16 + lr;
    #pragma unroll
    for (int kt = 0; kt < 4; ++kt)
      acc = __builtin_amdgcn_mfma_f32_16x16x32_f16(ha[kt], read_w(Wsb, col, lg * 16 + kt * 64), acc, 0, 0, 0);
    float bias = mb[col];
    #pragma unroll
    for (int j = 0; j < 4; ++j) {
      int srow = w * 16 + lg * 4 + j;
      int byte = srow * 256 + (((col * 2) ^ ((srow & 7) << 4)));
      *reinterpret_cast<f16*>(Sb + byte) = (f16)tanh_fast(acc[j] + bias);
    }
  }
  half8 ma[4];
  {
    int lrow = w * 16 + lr;
    #pragma unroll
    for (int kt = 0; kt < 4; ++kt) {
      int byte = lrow * 256 + ((lg * 16 + kt * 64) ^ ((lrow & 7) << 4));
      ma[kt] = *reinterpret_cast<const half8*>(Sb + byte);
    }
  }
  __syncthreads();

  // ---- phase G ----
  stage256<512, 32768>((const char*)gWt, Wsb, tid);
  __syncthreads();
  #pragma unroll
  for (int t = 0; t < 8; ++t) {
    f32x4 acc = {0.f, 0.f, 0.f, 0.f};
    int col = t * 16 + lr;
    #pragma unroll
    for (int kt = 0; kt < 4; ++kt)
      acc = __builtin_amdgcn_mfma_f32_16x16x32_f16(ma[kt], read_w(Wsb, col, lg * 16 + kt * 64), acc, 0, 0, 0);
    float bias = gb[col];
    #pragma unroll
    for (int j = 0; j < 4; ++j) {
      int grow = r0 + lg * 4 + j;
      if (grow < n)
        P[(size_t)grow * PROW + col] = (f16)fminf(__expf(acc[j] + bias), 60000.f);
    }
  }
  __syncthreads();

  // ---- phase V (w re-read from P) ----
  stage256<512, 32768>((const char*)aWt, Wsb, tid);
  __syncthreads();
  #pragma unroll
  for (int t = 0; t < 8; ++t) {
    f32x4 acc = {0.f, 0.f, 0.f, 0.f};
    int col = t * 16 + lr;
    #pragma unroll
    for (int kt = 0; kt < 4; ++kt)
      acc = __builtin_amdgcn_mfma_f32_16x16x32_f16(ma[kt], read_w(Wsb, col, lg * 16 + kt * 64), acc, 0, 0, 0);
    float bias = ab[col];
    #pragma unroll
    for (int j = 0; j < 4; ++j) {
      int grow = r0 + lg * 4 + j;
      if (grow < n) {
        float wld = (float)P[(size_t)grow * PROW + col];
        P[(size_t)grow * PROW + 128 + col] = (f16)(wld * tanh_fast(acc[j] + bias));
      }
    }
  }
}

// ---------------- fused upd + decoder (layer 2 end) ----------------
__global__ __launch_bounds__(512, 4) void upddec_kernel(
    const f16* __restrict__ h, const f16* __restrict__ ag,
    const f16* __restrict__ uWt, const float* __restrict__ ub,
    const f16* __restrict__ d1Wt, const float* __restrict__ d1b,
    const float* __restrict__ d2W, const float* __restrict__ d2b,
    float* __restrict__ out, int n) {
  __shared__ f16 Ws[128 * 128];
  __shared__ f16 Ss[128 * 128];
  char* Wsb = reinterpret_cast<char*>(Ws);
  char* Sb = reinterpret_cast<char*>(Ss);
  const int tid = threadIdx.x;
  const int w = tid >> 6, lane = tid & 63;
  const int lr = lane & 15, lg = lane >> 4;
  const int r0 = blockIdx.x * 128 + w * 16;

  half8 ah[4], aa[4];
  {
    int rr = r0 + lr;
    if (rr >= n) rr = n - 1;
    const f16* ap = h + (size_t)rr * ED + lg * 8;
    const f16* bp = ag + (size_t)rr * ED + lg * 8;
    #pragma unroll
    for (int kt = 0; kt < 4; ++kt) {
      ah[kt] = *reinterpret_cast<const half8*>(ap + kt * 32);
      aa[kt] = *reinterpret_cast<const half8*>(bp + kt * 32);
    }
  }

  // ---- phase U (column halves) -> stripe only ----
  #pragma unroll
  for (int half = 0; half < 2; ++half) {
    __syncthreads();
    stage512<512>((const char*)uWt + (size_t)half * 64 * 512, Wsb, tid);
    __syncthreads();
    #pragma unroll
    for (int t = 0; t < 4; ++t) {
      int colL = t * 16 + lr;
      int col = half * 64 + colL;
      f32x4 acc = {0.f, 0.f, 0.f, 0.f};
      #pragma unroll
      for (int kt = 0; kt < 4; ++kt)
        acc = __builtin_amdgcn_mfma_f32_16x16x32_f16(ah[kt], read_w512(Wsb, colL, lg * 16 + kt * 64), acc, 0, 0, 0);
      #pragma unroll
      for (int kt = 0; kt < 4; ++kt)
        acc = __builtin_amdgcn_mfma_f32_16x16x32_f16(aa[kt], read_w512(Wsb, colL, 256 + lg * 16 + kt * 64), acc, 0, 0, 0);
      float bias = ub[col];
      #pragma unroll
      for (int j = 0; j < 4; ++j) {
        int srow = w * 16 + lg * 4 + j;
        int byte = srow * 256 + (((col * 2) ^ ((srow & 7) << 4)));
        *reinterpret_cast<f16*>(Sb + byte) = (f16)tanh_fast(acc[j] + bias);
      }
    }
  }
  half8 ha[4];
  {
    int lrow = w * 16 + lr;
    #pragma unroll
    for (int kt = 0; kt < 4; ++kt) {
      int byte = lrow * 256 + ((lg * 16 + kt * 64) ^ ((lrow & 7) << 4));
      ha[kt] = *reinterpret_cast<const half8*>(Sb + byte);
    }
  }
  __syncthreads();

  // ---- decoder: y = tanh(h3@d1W+d1b); out = y@d2W + d2b ----
  stage256<512, 16384>((const char*)d1Wt, Wsb, tid);   // 64 cols x 128 k
  __syncthreads();
  float rowsum[4] = {0.f, 0.f, 0.f, 0.f};
  #pragma unroll
  for (int t = 0; t < 4; ++t) {
    f32x4 acc = {0.f, 0.f, 0.f, 0.f};
    int col = t * 16 + lr;
    #pragma unroll
    for (int kt = 0; kt < 4; ++kt)
      acc = __builtin_amdgcn_mfma_f32_16x16x32_f16(ha[kt], read_w(Wsb, col, lg * 16 + kt * 64), acc, 0, 0, 0);
    float b1 = d1b[col], w2 = d2W[col];
    #pragma unroll
    for (int j = 0; j < 4; ++j) rowsum[j] += tanh_fast(acc[j] + b1) * w2;
  }
  #pragma unroll
  for (int d = 1; d < 16; d <<= 1) {
    #pragma unroll
    for (int j = 0; j < 4; ++j) rowsum[j] += __shfl_xor(rowsum[j], d, 64);
  }
  if (lr == 0) {
    #pragma unroll
    for (int j = 0; j < 4; ++j) {
      int grow = r0 + lg * 4 + j;
      if (grow < n) out[grow] = rowsum[j] + d2b[0];
    }
  }
}

// ---------------- edge aggregation: one wave per dst node, pure gather-sum ---
// (round-10 version; pinned at ~3.2 TB/s beyond-L2 random-gather ceiling)
__global__ __launch_bounds__(256) void edge_aggr_kernel(
    const int* __restrict__ offs, const int* __restrict__ ssrc,
    const f16* __restrict__ P, f16* __restrict__ aggr, int n) {
  int i = blockIdx.x * 4 + (threadIdx.x >> 6);
  if (i >= n) return;
  int lane = threadIdx.x & 63;
  int s0 = offs[i], s1 = offs[i + 1];
  const char* Pb = reinterpret_cast<const char*>(P);

  float4 acc = {0.f, 0.f, 0.f, 0.f};
  #pragma unroll 4
  for (int e = s0; e < s1; ++e) {
    int sn = ssrc[e];
    half4 x = *reinterpret_cast<const half4*>(Pb + (size_t)sn * 512 + lane * 8);
    acc.x += (float)x.x;
    acc.y += (float)x.y;
    acc.z += (float)x.z;
    acc.w += (float)x.w;
  }
  float px = __shfl(acc.x, lane ^ 32, 64);
  float py = __shfl(acc.y, lane ^ 32, 64);
  float pz = __shfl(acc.z, lane ^ 32, 64);
  float pw = __shfl(acc.w, lane ^ 32, 64);
  if (lane >= 32) {
    half4 o;
    o.x = (f16)(acc.x / (px + 1e-16f));
    o.y = (f16)(acc.y / (py + 1e-16f));
    o.z = (f16)(acc.z / (pz + 1e-16f));
    o.w = (f16)(acc.w / (pw + 1e-16f));
    *reinterpret_cast<half4*>(
        reinterpret_cast<char*>(aggr) + (size_t)i * 256 + (size_t)(lane - 32) * 8) = o;
  }
}

// ---------------- host ----------------
extern "C" void kernel_launch(void* const* d_in, const int* in_sizes, int n_in,
                              void* d_out, int out_size, void* d_ws, size_t ws_size,
                              hipStream_t stream) {
  const float* node_feature = (const float*)d_in[0];
  const int*   edge_index   = (const int*)d_in[1];
  const float* enc_W  = (const float*)d_in[3];
  const float* enc_b  = (const float*)d_in[4];
  const float* gate_W = (const float*)d_in[5];
  const float* gate_b = (const float*)d_in[6];
  const float* att_W  = (const float*)d_in[7];
  const float* att_b  = (const float*)d_in[8];
  const float* msg_W  = (const float*)d_in[9];
  const float* msg_b  = (const float*)d_in[10];
  const float* upd_W  = (const float*)d_in[11];
  const float* upd_b  = (const float*)d_in[12];
  const float* dec1_W = (const float*)d_in[13];
  const float* dec1_b = (const float*)d_in[14];
  const float* dec2_W = (const float*)d_in[15];
  const float* dec2_b = (const float*)d_in[16];

  const int n = in_sizes[0] / 2;   // 50000
  const int E = in_sizes[1] / 2;   // 800000
  const int* src = edge_index;
  const int* dst = edge_index + E;

  char* ws = (char*)d_ws;
  size_t off = 0;
  auto alloc = [&](size_t bytes) -> void* {
    void* p = ws + off;
    off += (bytes + 255) & ~(size_t)255;
    return p;
  };
  f16* hA   = (f16*)alloc((size_t)n * ED * 2);
  f16* hB   = (f16*)alloc((size_t)n * ED * 2);
  f16* P    = (f16*)alloc((size_t)n * PROW * 2);
  f16* aggr = (f16*)alloc((size_t)n * ED * 2);
  int* deg    = (int*)alloc((size_t)n * 4);
  int* offs   = (int*)alloc((size_t)(n + 1) * 4);
  int* cursor = (int*)alloc((size_t)n * 4);
  int* ssrc   = (int*)alloc((size_t)E * 4);
  f16* msgT  = (f16*)alloc((size_t)3 * ED * ED * 2);
  f16* gateT = (f16*)alloc((size_t)3 * ED * ED * 2);
  f16* attT  = (f16*)alloc((size_t)3 * ED * ED * 2);
  f16* updT  = (f16*)alloc((size_t)3 * ED * 2 * ED * 2);
  f16* dec1T = (f16*)alloc((size_t)ED * 64 * 2);

  // weight prep (once per call)
  {
    int tot3 = 3 * 3 * ED * ED;
    transpose3_kernel<<<(tot3 + 255) / 256, 256, 0, stream>>>(
        msg_W, gate_W, att_W, msgT, gateT, attT);
    int totu = 3 * 2 * ED * ED;
    transpose_w_kernel<<<(totu + 255) / 256, 256, 0, stream>>>(
        upd_W, updT, 2 * ED, ED, totu);
    int totd = ED * 64;
    transpose_w_kernel<<<(totd + 255) / 256, 256, 0, stream>>>(
        dec1_W, dec1T, ED, 64, totd);
  }

  // CSR build (once per call)
  hipMemsetAsync(deg, 0, (size_t)n * 4, stream);
  count_deg_kernel<<<(E + 255) / 256, 256, 0, stream>>>(dst, deg, E);
  scan_kernel<<<1, 1024, 0, stream>>>(deg, offs, cursor, n);
  scatter_kernel<<<(E + 255) / 256, 256, 0, stream>>>(src, dst, cursor, ssrc, E);

  // encoder
  encoder_kernel<<<((size_t)n * ED + 255) / 256, 256, 0, stream>>>(
      node_feature, enc_W, enc_b, hA, n);

  const int gemm_grid = (n + 127) / 128;   // 512-thread blocks, 128 rows
  const int aggr_grid = (n + 3) / 4;

  // layer 0 MGV
  gemm_mgv_kernel<<<gemm_grid, 512, 0, stream>>>(
      hA, msgT, msg_b, gateT, gate_b, attT, att_b, P, n);
  edge_aggr_kernel<<<aggr_grid, 256, 0, stream>>>(offs, ssrc, P, aggr, n);

  // upd0 + MGV1
  updmgv_kernel<<<gemm_grid, 512, 0, stream>>>(
      hA, aggr, updT, upd_b,
      msgT + (size_t)1 * ED * ED, msg_b + ED,
      gateT + (size_t)1 * ED * ED, gate_b + ED,
      attT + (size_t)1 * ED * ED, att_b + ED,
      hB, P, n);
  edge_aggr_kernel<<<aggr_grid, 256, 0, stream>>>(offs, ssrc, P, aggr, n);

  // upd1 + MGV2
  updmgv_kernel<<<gemm_grid, 512, 0, stream>>>(
      hB, aggr, updT + (size_t)1 * 2 * ED * ED, upd_b + ED,
      msgT + (size_t)2 * ED * ED, msg_b + 2 * ED,
      gateT + (size_t)2 * ED * ED, gate_b + 2 * ED,
      attT + (size_t)2 * ED * ED, att_b + 2 * ED,
      hA, P, n);
  edge_aggr_kernel<<<aggr_grid, 256, 0, stream>>>(offs, ssrc, P, aggr, n);

  // upd2 + decoder
  upddec_kernel<<<gemm_grid, 512, 0, stream>>>(
      hA, aggr, updT + (size_t)2 * 2 * ED * ED, upd_b + 2 * ED,
      dec1T, dec1_b, dec2_W, dec2_b, (float*)d_out, n);
}